// Round 3
// baseline (674.182 us; speedup 1.0000x reference)
//
#include <hip/hip_runtime.h>
#include <hip/hip_fp16.h>

// ---------------------------------------------------------------------------
// SGCN: 2-layer GraphSAGE('gcn') + EdgeWeightNorm('right') + mean-pool + FC
// N=100k nodes, E=3.2M edges, G=64 graphs, F=64 feats.
//
// R13 -> R14:
//  * binfill2 (95us) + csrsort were latency-bound structural overhead: each
//    edge moved through memory 3x (LDS stage -> fragmented flush -> re-read
//    -> sorted write), with nothing saturated (HBM 8%, VALU 20%).
//  * Replaced by direct build: k_cnt (global per-node counts), k_offp
//    (pair-padded slot reservation via wave-aggregated atomic cursor),
//    k_fillp (scatter packed 4B entries; lines stay L2-resident).
//    Pad slots zeroed by an async memset of the csr region.
//  * k_agg_p and all downstream kernels unchanged (same off/fill/csr
//    contract: pair (2i,2i+1) has round8(max(c0,c1)) slots each, pads = 0,
//    entry = src(17b) | fp16-weight-sans-sign(15b) << 17).
// Pipeline: memset x2, cvt, cnt, offp, fillp, agg, fc, agg, fcpool, out.
// ---------------------------------------------------------------------------

#define SRC17 0x1FFFFu

__device__ __forceinline__ float readlane_f(float v, int l) {
    return __int_as_float(__builtin_amdgcn_readlane(__float_as_int(v), l));
}

__device__ __forceinline__ int2 ntload_i2(const int2* p) {
    unsigned long long r = __builtin_nontemporal_load((const unsigned long long*)p);
    return make_int2((int)(unsigned)(r & 0xffffffffull), (int)(unsigned)(r >> 32));
}

__device__ __forceinline__ void ntstore_f2(float2* p, float2 v) {
    union { float2 f; unsigned long long u; } c;
    c.f = v;
    __builtin_nontemporal_store(c.u, (unsigned long long*)p);
}

// fp32 -> fp16 bulk convert (float4 -> 2x half2 per thread)
__global__ void k_cvt(const float4* __restrict__ x, uint2* __restrict__ xh, int n4) {
    int i = blockIdx.x * blockDim.x + threadIdx.x;
    if (i >= n4) return;
    float4 v = x[i];
    __half2 a = __floats2half2_rn(v.x, v.y);
    __half2 b = __floats2half2_rn(v.z, v.w);
    uint2 r;
    r.x = *(const unsigned*)&a;
    r.y = *(const unsigned*)&b;
    xh[i] = r;
}

// per-node in-degree via global atomics
__global__ void k_cnt(const int* __restrict__ edst, int* __restrict__ cnt, int E) {
    int e = blockIdx.x * blockDim.x + threadIdx.x;
    if (e < E) atomicAdd(&cnt[edst[e]], 1);
}

// pair-padded slot reservation: thread = node pair (2i, 2i+1).
// pc = round8(max(c0,c1)); pair gets 2*pc slots (node0 at base, node1 at
// base+pc) reserved via one wave-aggregated atomicAdd on a global cursor.
// Layout is placement-nondeterministic but per-node content-deterministic.
__global__ __launch_bounds__(256) void k_offp(
        const int* __restrict__ cnt, int* __restrict__ off,
        int* __restrict__ cursor, int N) {
    const int i     = blockIdx.x * blockDim.x + threadIdx.x;   // pair index
    const int npair = (N + 1) >> 1;
    const int lane  = threadIdx.x & 63;
    int sz = 0, pc = 0;
    if (i < npair) {
        int c0 = cnt[2 * i];
        int c1 = (2 * i + 1 < N) ? cnt[2 * i + 1] : 0;
        pc = (max(c0, c1) + 7) & ~7;
        sz = 2 * pc;
    }
    int pref = sz;
    #pragma unroll
    for (int d = 1; d < 64; d <<= 1) {
        int t = __shfl_up(pref, d);
        if (lane >= d) pref += t;
    }
    int total = __shfl(pref, 63);
    int base  = 0;
    if (lane == 63 && total > 0) base = atomicAdd(cursor, total);
    base = __shfl(base, 63);
    if (i < npair) {
        int b = base + pref - sz;
        off[2 * i] = b;
        if (2 * i + 1 < N) off[2 * i + 1] = b + pc;
    }
}

// scatter packed edges into reserved slots. fill[] starts at 0.
__global__ void k_fillp(const int* __restrict__ esrc, const int* __restrict__ edst,
                        const float* __restrict__ ew, const int* __restrict__ off,
                        int* __restrict__ fill, unsigned* __restrict__ csr, int E) {
    int e = blockIdx.x * blockDim.x + threadIdx.x;
    if (e >= E) return;
    int d = edst[e];
    int p = atomicAdd(&fill[d], 1);
    unsigned h15 = (unsigned)__half_as_ushort(__float2half_rn(ew[e])) & 0x7FFFu;
    csr[off[d] + p] = ((unsigned)esrc[e] & SRC17) | (h15 << 17);
}

// ---- fallback kernels ----
__global__ void k_fill_pad(const int* __restrict__ esrc, const int* __restrict__ edst,
                           const float* __restrict__ ew, int* __restrict__ fill,
                           int2* __restrict__ csr, int E, int CAP) {
    int e = blockIdx.x * blockDim.x + threadIdx.x;
    if (e < E) {
        int d = edst[e];
        int p = atomicAdd(&fill[d], 1);
        if (p < CAP)
            csr[(size_t)d * CAP + p] = make_int2(esrc[e], __float_as_int(ew[e]));
    }
}

__global__ void k_off(const int* __restrict__ cnt, int* __restrict__ off,
                      int* __restrict__ fill, int* __restrict__ cursor, int N) {
    int i    = blockIdx.x * blockDim.x + threadIdx.x;
    int lane = threadIdx.x & 63;
    int c    = (i < N) ? cnt[i] : 0;
    int pref = c;
    #pragma unroll
    for (int d = 1; d < 64; d <<= 1) {
        int t = __shfl_up(pref, d);
        if (lane >= d) pref += t;
    }
    int total = __shfl(pref, 63);
    int base  = 0;
    if (lane == 63) base = atomicAdd(cursor, total);
    base = __shfl(base, 63);
    if (i < N) {
        int p = base + pref - c;
        off[i]  = p;
        fill[i] = p;
    }
}

__global__ void k_fill(const int* __restrict__ esrc, const int* __restrict__ edst,
                       const float* __restrict__ ew, int* __restrict__ fill,
                       int2* __restrict__ csr, int E) {
    int e = blockIdx.x * blockDim.x + threadIdx.x;
    if (e < E) {
        int d = edst[e];
        int p = atomicAdd(&fill[d], 1);
        csr[p] = make_int2(esrc[e], __float_as_int(ew[e]));
    }
}

// main-path gather-aggregate: wave = node PAIR. slot=lane>>5 owns node
// 2p+slot; f8=lane&31 covers the full 64-feat row as half2. Edge stream is
// packed 4 B, pair-padded to round8 with zeros -> guard-free inner loop,
// no shuffles, no cross-lane reductions.
__global__ __launch_bounds__(256, 6) void k_agg_p(
        const unsigned* __restrict__ xh, const int* __restrict__ off,
        const int* __restrict__ cnt_arr, const unsigned* __restrict__ csr,
        float* __restrict__ agg, int N) {
    const int lane = threadIdx.x & 63;
    const int slot = lane >> 5;
    const int f8   = lane & 31;
    const int wq   = (blockIdx.x * blockDim.x + threadIdx.x) >> 6;
    const int nw   = (gridDim.x * blockDim.x) >> 6;
    const int npair = (N + 1) >> 1;

    for (int pr = wq; pr < npair; pr += nw) {
        const int  node  = 2 * pr + slot;
        const bool valid = node < N;
        const int  cnt_s = valid ? cnt_arr[node] : 0;
        const int  st_s  = valid ? off[node] : 0;
        const int  cA = __builtin_amdgcn_readlane(cnt_s, 0);
        const int  cB = __builtin_amdgcn_readlane(cnt_s, 32);
        const int  pc = (max(cA, cB) + 7) & ~7;     // == k_offp's pair pad

        float2 acc = {0.f, 0.f};
        float  sw  = 0.f;
        const unsigned* __restrict__ pS = csr + st_s;
        for (int k = 0; k < pc; k += 8) {
            // broadcast edge fetch: same addr across the slot's 32 lanes
            uint4 e0 = *(const uint4*)(pS + k);
            uint4 e1 = *(const uint4*)(pS + k + 4);
            unsigned ev[8] = {e0.x, e0.y, e0.z, e0.w, e1.x, e1.y, e1.z, e1.w};
            float    w[8];
            unsigned u[8];
            #pragma unroll
            for (int t = 0; t < 8; ++t) {
                unsigned e = ev[t];
                w[t] = __half2float(__ushort_as_half((unsigned short)(e >> 17)));
                u[t] = xh[((e & SRC17) << 5) | (unsigned)f8];
            }
            #pragma unroll
            for (int t = 0; t < 8; ++t) {
                float2 v = __half22float2(*(const __half2*)&u[t]);
                acc.x = fmaf(w[t], v.x, acc.x);
                acc.y = fmaf(w[t], v.y, acc.y);
                sw += w[t];
            }
        }
        if (valid) {
            float invw = (sw > 0.f) ? (1.f / sw) : 0.f;
            float invd = 1.f / ((float)cnt_s + 1.f);
            unsigned us = xh[((unsigned)node << 5) | (unsigned)f8];
            float2 xs = __half22float2(*(const __half2*)&us);
            float2 hn;
            hn.x = (acc.x * invw + xs.x) * invd;
            hn.y = (acc.y * invw + xs.y) * invd;
            ntstore_f2(&((float2*)agg)[(size_t)node * 32 + f8], hn);
        }
    }
}

// fallback gather-aggregate (int2 csr, fp16 x).
__global__ __launch_bounds__(256, 4) void k_agg_f(
        const unsigned* __restrict__ xh, const int* __restrict__ off,
        const int* __restrict__ cnt_arr, const int2* __restrict__ csr,
        float* __restrict__ agg, int N, int CAP) {
    const int lane   = threadIdx.x & 63;
    const int slot   = lane >> 5;
    const int f8     = lane & 31;
    const int wave   = (blockIdx.x * blockDim.x + threadIdx.x) >> 6;
    const int nwaves = (gridDim.x * blockDim.x) >> 6;

    int node  = wave;
    int cnt_p = 0, start_p = 0;
    if (node < N) {
        cnt_p   = cnt_arr[node];
        start_p = (CAP > 0) ? node * CAP : off[node];
        if (CAP > 0) cnt_p = min(cnt_p, CAP);
    }
    for (; node < N; node += nwaves) {
        const int cnt = cnt_p, start = start_p;
        int nn = node + nwaves;
        if (nn < N) {
            cnt_p   = cnt_arr[nn];
            start_p = (CAP > 0) ? nn * CAP : off[nn];
            if (CAP > 0) cnt_p = min(cnt_p, CAP);
        }
        int2 ee = make_int2(0, 0);
        if (lane < cnt) ee = ntload_i2(&csr[start + lane]);
        float2 acc0 = {0.f, 0.f}, acc1 = {0.f, 0.f};
        float  sw = 0.0f;
        for (int bk = 0; bk < cnt; bk += 64) {
            int   s_l = ee.x;
            float w_l = __int_as_float(ee.y);
            int2 en = make_int2(0, 0);
            int  rem = cnt - bk - 64;
            if (lane < rem) en = ntload_i2(&csr[start + bk + 64 + lane]);
            sw += w_l;
            #pragma unroll
            for (int half = 0; half < 2; ++half) {
                float    w[16];
                unsigned u[16];
                #pragma unroll
                for (int k = 0; k < 16; ++k) {
                    int idx = half * 32 + 2 * k + slot;
                    int s   = __shfl(s_l, idx);
                    w[k]    = __shfl(w_l, idx);
                    u[k]    = xh[(size_t)s * 32 + f8];
                }
                #pragma unroll
                for (int k = 0; k < 16; k += 2) {
                    float2 v0 = __half22float2(*(const __half2*)&u[k]);
                    float2 v1 = __half22float2(*(const __half2*)&u[k + 1]);
                    acc0.x = fmaf(w[k],     v0.x, acc0.x);
                    acc0.y = fmaf(w[k],     v0.y, acc0.y);
                    acc1.x = fmaf(w[k + 1], v1.x, acc1.x);
                    acc1.y = fmaf(w[k + 1], v1.y, acc1.y);
                }
            }
            ee = en;
        }
        acc0.x += acc1.x; acc0.y += acc1.y;
        acc0.x += __shfl_xor(acc0.x, 32);
        acc0.y += __shfl_xor(acc0.y, 32);
        #pragma unroll
        for (int mask = 1; mask <= 32; mask <<= 1) sw += __shfl_xor(sw, mask);
        float invw = (sw > 0.0f) ? (1.0f / sw) : 0.0f;
        float invd = 1.0f / ((float)cnt + 1.0f);
        if (lane < 32) {
            unsigned us = xh[(size_t)node * 32 + f8];
            float2 xs = __half22float2(*(const __half2*)&us);
            float2 hn;
            hn.x = (acc0.x * invw + xs.x) * invd;
            hn.y = (acc0.y * invw + xs.y) * invd;
            ntstore_f2(&((float2*)agg)[(size_t)node * 32 + f8], hn);
        }
    }
}

// k_fc: h = relu(agg @ W + b), emitted as fp16 (feeds the next agg gather).
// Per-lane W column in regs; readlane inner.
__global__ __launch_bounds__(256) void k_fc(
        const float* __restrict__ agg, const float* __restrict__ W,
        const float* __restrict__ b, __half* __restrict__ outh, int N) {
    const int lane   = threadIdx.x & 63;
    const int wave   = (blockIdx.x * blockDim.x + threadIdx.x) >> 6;
    const int nwaves = (gridDim.x * blockDim.x) >> 6;
    float wc[64];
    #pragma unroll
    for (int f = 0; f < 64; ++f) wc[f] = W[f * 64 + lane];   // coalesced rows
    const float bias = b[lane];
    for (int node = wave; node < N; node += nwaves) {
        float hn = agg[(size_t)node * 64 + lane];
        float o0 = bias, o1 = 0.f, o2 = 0.f, o3 = 0.f;
        #pragma unroll
        for (int f = 0; f < 64; f += 4) {
            o0 = fmaf(readlane_f(hn, f),     wc[f],     o0);
            o1 = fmaf(readlane_f(hn, f + 1), wc[f + 1], o1);
            o2 = fmaf(readlane_f(hn, f + 2), wc[f + 2], o2);
            o3 = fmaf(readlane_f(hn, f + 3), wc[f + 3], o3);
        }
        float o = fmaxf((o0 + o1) + (o2 + o3), 0.0f);
        outh[(size_t)node * 64 + lane] = __float2half_rn(o);
    }
}

// fc (with relu) + mean-pool fused; gid sorted -> run-length flush.
__global__ __launch_bounds__(256) void k_fcpool(
        const float* __restrict__ agg, const float* __restrict__ W,
        const float* __restrict__ b, const int* __restrict__ gid,
        float* __restrict__ hg, float* __restrict__ cntg, int N) {
    const int lane   = threadIdx.x & 63;
    const int wave   = (blockIdx.x * blockDim.x + threadIdx.x) >> 6;
    const int nwaves = (gridDim.x * blockDim.x) >> 6;
    float wc[64];
    #pragma unroll
    for (int f = 0; f < 64; ++f) wc[f] = W[f * 64 + lane];
    const float bias = b[lane];
    const int per   = (N + nwaves - 1) / nwaves;
    const int start = wave * per;
    const int end   = min(N, start + per);
    if (start >= N) return;

    int   curg = -1;
    float acc  = 0.0f;
    int   c    = 0;
    for (int node = start; node < end; ++node) {
        float hn = agg[(size_t)node * 64 + lane];
        float o0 = bias, o1 = 0.f, o2 = 0.f, o3 = 0.f;
        #pragma unroll
        for (int f = 0; f < 64; f += 4) {
            o0 = fmaf(readlane_f(hn, f),     wc[f],     o0);
            o1 = fmaf(readlane_f(hn, f + 1), wc[f + 1], o1);
            o2 = fmaf(readlane_f(hn, f + 2), wc[f + 2], o2);
            o3 = fmaf(readlane_f(hn, f + 3), wc[f + 3], o3);
        }
        float o = fmaxf((o0 + o1) + (o2 + o3), 0.0f);
        int g = gid[node];
        if (g != curg) {
            if (c > 0) {
                atomicAdd(&hg[curg * 64 + lane], acc);
                if (lane == 0) atomicAdd(&cntg[curg], (float)c);
            }
            curg = g; acc = 0.0f; c = 0;
        }
        acc += o;
        ++c;
    }
    if (c > 0) {
        atomicAdd(&hg[curg * 64 + lane], acc);
        if (lane == 0) atomicAdd(&cntg[curg], (float)c);
    }
}

__global__ void k_out(const float* __restrict__ hg, const float* __restrict__ cntg,
                      const float* __restrict__ Wc, const float* __restrict__ bc,
                      float* __restrict__ out, int G) {
    int t = blockIdx.x * blockDim.x + threadIdx.x;
    if (t >= G * 2) return;
    int g = t >> 1, c = t & 1;
    float ct = fmaxf(cntg[g], 1.0f);
    float o  = bc[c];
    for (int f = 0; f < 64; ++f)
        o += (hg[g * 64 + f] / ct) * Wc[f * 2 + c];
    out[t] = o;
}

extern "C" void kernel_launch(void* const* d_in, const int* in_sizes, int n_in,
                              void* d_out, int out_size, void* d_ws, size_t ws_size,
                              hipStream_t stream) {
    const float* in_feat = (const float*)d_in[0];
    const float* ew      = (const float*)d_in[1];
    const float* W1      = (const float*)d_in[2];
    const float* b1      = (const float*)d_in[3];
    const float* W2      = (const float*)d_in[4];
    const float* b2      = (const float*)d_in[5];
    const float* Wc      = (const float*)d_in[6];
    const float* bc      = (const float*)d_in[7];
    const int*   esrc    = (const int*)d_in[8];
    const int*   edst    = (const int*)d_in[9];
    const int*   gid     = (const int*)d_in[10];

    const int E = in_sizes[1];
    const int N = in_sizes[10];
    const int G = out_size / 2;
    float* outp = (float*)d_out;

    auto alignup = [](size_t x) { return (x + 15) & ~(size_t)15; };
    char* base = (char*)d_ws;
    const int FC_BLK = 1024, AGG_BLK = 2048;
    const int n4 = N * 16;                             // N*64/4 float4s
    const int npair = (N + 1) >> 1;

    // ---- main path: direct pair-padded packed CSR build ----
    // csr capacity: sum 2*round8(max(c0,c1)) <= 2E + 7N  -> use 2E + 8N
    size_t csr_cap = 2 * (size_t)E + 8 * (size_t)N;

    size_t zhdr  = ((size_t)G * 64 + G + 4 + 2 * (size_t)N) * 4; // hg,cntg,cursor,cnt,fill
    size_t o_off = alignup(zhdr);
    size_t o_csr = o_off + alignup((size_t)N * 4);
    size_t o_t1  = o_csr + alignup(csr_cap * 4);
    size_t o_t2  = o_t1 + alignup((size_t)N * 64 * 4);
    size_t o_xh  = o_t2 + alignup((size_t)N * 64 * 4);
    size_t o_th  = o_xh + alignup((size_t)N * 64 * 2);
    size_t needB = o_th + (size_t)N * 64 * 2;

    if (ws_size >= needB && N <= (1 << 17)) {
        float*    hg     = (float*)base;
        float*    cntg   = hg + (size_t)G * 64;
        int*      cursor = (int*)(cntg + G);
        int*      cnt    = cursor + 4;
        int*      fill   = cnt + N;
        int*      off    = (int*)(base + o_off);
        unsigned* csr    = (unsigned*)(base + o_csr);
        float*    t1     = (float*)(base + o_t1);
        float*    t2     = (float*)(base + o_t2);
        unsigned* xh0    = (unsigned*)(base + o_xh);
        __half*   th1    = (__half*)(base + o_th);

        hipMemsetAsync(d_ws, 0, zhdr, stream);          // hg,cntg,cursor,cnt,fill
        hipMemsetAsync(csr, 0, csr_cap * 4, stream);    // pad slots stay 0
        k_cvt  <<<(n4 + 255) / 256, 256, 0, stream>>>((const float4*)in_feat, (uint2*)xh0, n4);
        k_cnt  <<<(E + 255) / 256, 256, 0, stream>>>(edst, cnt, E);
        k_offp <<<(npair + 255) / 256, 256, 0, stream>>>(cnt, off, cursor, N);
        k_fillp<<<(E + 255) / 256, 256, 0, stream>>>(esrc, edst, ew, off, fill, csr, E);
        k_agg_p <<<AGG_BLK, 256, 0, stream>>>(xh0, off, cnt, csr, t1, N);
        k_fc    <<<FC_BLK, 256, 0, stream>>>(t1, W1, b1, th1, N);
        k_agg_p <<<AGG_BLK, 256, 0, stream>>>((const unsigned*)th1, off, cnt, csr, t2, N);
        k_fcpool<<<FC_BLK, 256, 0, stream>>>(t2, W2, b2, gid, hg, cntg, N);
        k_out   <<<1, 128, 0, stream>>>(hg, cntg, Wc, bc, outp, G);
        return;
    }

    // ---- fallback 1: one-pass padded scatter + k_agg_f ----
    const int CAP = 96;
    size_t hdr    = ((size_t)G * 64 + G + 1 + N) * 4;
    size_t needB2 = alignup(hdr) + alignup((size_t)N * CAP * 8)
                  + alignup((size_t)N * 64 * 4) * 2
                  + alignup((size_t)N * 64 * 2) * 2;
    if (ws_size >= needB2) {
        size_t o = 0;
        float* hg     = (float*)(base + o);
        float* cntg   = hg + (size_t)G * 64;
        int*   fill   = (int*)(cntg + G) + 1;
        o += alignup(hdr);
        int2*     csr = (int2*)(base + o);    o += alignup((size_t)N * CAP * 8);
        float*    t1  = (float*)(base + o);   o += alignup((size_t)N * 64 * 4);
        float*    t2  = (float*)(base + o);   o += alignup((size_t)N * 64 * 4);
        unsigned* xh0 = (unsigned*)(base + o); o += alignup((size_t)N * 64 * 2);
        __half*   th1 = (__half*)(base + o);

        hipMemsetAsync(d_ws, 0, hdr, stream);
        k_cvt     <<<(n4 + 255) / 256, 256, 0, stream>>>((const float4*)in_feat, (uint2*)xh0, n4);
        k_fill_pad<<<(E + 255) / 256, 256, 0, stream>>>(esrc, edst, ew, fill, csr, E, CAP);
        k_agg_f <<<AGG_BLK, 256, 0, stream>>>(xh0, (const int*)nullptr, fill, csr, t1, N, CAP);
        k_fc    <<<FC_BLK, 256, 0, stream>>>(t1, W1, b1, th1, N);
        k_agg_f <<<AGG_BLK, 256, 0, stream>>>((const unsigned*)th1, (const int*)nullptr, fill, csr, t2, N, CAP);
        k_fcpool<<<FC_BLK, 256, 0, stream>>>(t2, W2, b2, gid, hg, cntg, N);
        k_out   <<<1, 128, 0, stream>>>(hg, cntg, Wc, bc, outp, G);
        return;
    }

    // ---- fallback 2: 3-pass compact CSR ----
    {
        size_t o = 0;
        float* hg     = (float*)(base + o);
        float* cntg   = hg + (size_t)G * 64;
        int*   cursor = (int*)(cntg + G);
        int*   cnt    = cursor + 1;
        o += alignup(hdr);
        int*      off  = (int*)(base + o);    o += alignup((size_t)N * 4);
        int*      fill = (int*)(base + o);    o += alignup((size_t)N * 4);
        int2*     csr  = (int2*)(base + o);   o += alignup((size_t)E * 8);
        float*    t1   = (float*)(base + o);  o += alignup((size_t)N * 64 * 4);
        float*    t2   = (float*)(base + o);  o += alignup((size_t)N * 64 * 4);
        unsigned* xh0  = (unsigned*)(base + o); o += alignup((size_t)N * 64 * 2);
        __half*   th1  = (__half*)(base + o);

        hipMemsetAsync(d_ws, 0, hdr, stream);
        k_cvt <<<(n4 + 255) / 256, 256, 0, stream>>>((const float4*)in_feat, (uint2*)xh0, n4);
        k_cnt <<<(E + 255) / 256, 256, 0, stream>>>(edst, cnt, E);
        k_off <<<(N + 255) / 256, 256, 0, stream>>>(cnt, off, fill, cursor, N);
        k_fill<<<(E + 255) / 256, 256, 0, stream>>>(esrc, edst, ew, fill, csr, E);
        k_agg_f <<<AGG_BLK, 256, 0, stream>>>(xh0, off, cnt, csr, t1, N, 0);
        k_fc    <<<FC_BLK, 256, 0, stream>>>(t1, W1, b1, th1, N);
        k_agg_f <<<AGG_BLK, 256, 0, stream>>>((const unsigned*)th1, off, cnt, csr, t2, N, 0);
        k_fcpool<<<FC_BLK, 256, 0, stream>>>(t2, W2, b2, gid, hg, cntg, N);
        k_out   <<<1, 128, 0, stream>>>(hg, cntg, Wc, bc, outp, G);
    }
}

// Round 4
// 577.927 us; speedup vs baseline: 1.1666x; 1.1666x over previous
//
#include <hip/hip_runtime.h>
#include <hip/hip_fp16.h>

// ---------------------------------------------------------------------------
// SGCN: 2-layer GraphSAGE('gcn') + EdgeWeightNorm('right') + mean-pool + FC
// N=100k nodes, E=3.2M edges, G=64 graphs, F=64 feats.
//
// R14 -> R15 (fixing R14's two regressions):
//  * off[] is now MONOTONE + deterministic via 3-kernel scan (psum/topscan/
//    offp2) -- R14's atomic-cursor placement randomized csr layout and broke
//    k_agg_p's streaming reads (the hidden ~200us).
//  * k_fillx: XCD-sliced scatter. Blocks grouped by blockIdx%8 (empirical
//    XCD round-robin); group x handles only dsts in node-slice x, so each
//    slice's ~3.6MB csr window is written by ONE XCD -> lines fill in that
//    L2 -> full-line writebacks (R14's k_fillp: 196MB write-amplified).
//    Heuristic is perf-only: any block may process its group's edges.
//  * Contract with k_agg_p unchanged: pair (2i,2i+1) gets round8(max) slots
//    each, pads zero, entry = src(17b) | fp16-weight-sans-sign(15b) << 17.
// Pipeline: memset x2, cvt, cnt, psum, topscan, offp2, fillx,
//           agg, fc, agg, fcpool, out.
// ---------------------------------------------------------------------------

#define SRC17 0x1FFFFu

__device__ __forceinline__ float readlane_f(float v, int l) {
    return __int_as_float(__builtin_amdgcn_readlane(__float_as_int(v), l));
}

__device__ __forceinline__ int2 ntload_i2(const int2* p) {
    unsigned long long r = __builtin_nontemporal_load((const unsigned long long*)p);
    return make_int2((int)(unsigned)(r & 0xffffffffull), (int)(unsigned)(r >> 32));
}

__device__ __forceinline__ void ntstore_f2(float2* p, float2 v) {
    union { float2 f; unsigned long long u; } c;
    c.f = v;
    __builtin_nontemporal_store(c.u, (unsigned long long*)p);
}

// fp32 -> fp16 bulk convert (float4 -> 2x half2 per thread)
__global__ void k_cvt(const float4* __restrict__ x, uint2* __restrict__ xh, int n4) {
    int i = blockIdx.x * blockDim.x + threadIdx.x;
    if (i >= n4) return;
    float4 v = x[i];
    __half2 a = __floats2half2_rn(v.x, v.y);
    __half2 b = __floats2half2_rn(v.z, v.w);
    uint2 r;
    r.x = *(const unsigned*)&a;
    r.y = *(const unsigned*)&b;
    xh[i] = r;
}

// per-node in-degree via global atomics
__global__ void k_cnt(const int* __restrict__ edst, int* __restrict__ cnt, int E) {
    int e = blockIdx.x * blockDim.x + threadIdx.x;
    if (e < E) atomicAdd(&cnt[edst[e]], 1);
}

// ---- deterministic monotone pair-padded offsets: 3-kernel scan ----
// pair i=(2i,2i+1): pc = round8(max(c0,c1)); pair size = 2*pc.

__global__ __launch_bounds__(256) void k_psum(
        const int* __restrict__ cnt, int* __restrict__ bsum, int N) {
    __shared__ int s[256];
    const int tid = threadIdx.x;
    const int i = blockIdx.x * 256 + tid;
    const int npair = (N + 1) >> 1;
    int sz = 0;
    if (i < npair) {
        int c0 = cnt[2 * i];
        int c1 = (2 * i + 1 < N) ? cnt[2 * i + 1] : 0;
        sz = 2 * ((max(c0, c1) + 7) & ~7);
    }
    s[tid] = sz;
    __syncthreads();
    #pragma unroll
    for (int o = 128; o > 0; o >>= 1) {
        if (tid < o) s[tid] += s[tid + o];
        __syncthreads();
    }
    if (tid == 0) bsum[blockIdx.x] = s[0];
}

// exclusive scan over nb (<=256) block sums, in place; single block.
__global__ __launch_bounds__(256) void k_topscan(int* __restrict__ bsum, int nb) {
    __shared__ int s[256];
    const int tid = threadIdx.x;
    int v = (tid < nb) ? bsum[tid] : 0;
    s[tid] = v;
    __syncthreads();
    for (int o = 1; o < 256; o <<= 1) {
        int t = (tid >= o) ? s[tid - o] : 0;
        __syncthreads();
        s[tid] += t;
        __syncthreads();
    }
    if (tid < nb) bsum[tid] = s[tid] - v;   // exclusive
}

__global__ __launch_bounds__(256) void k_offp2(
        const int* __restrict__ cnt, const int* __restrict__ bsum,
        int* __restrict__ off, int N) {
    __shared__ int s[256];
    const int tid = threadIdx.x;
    const int i = blockIdx.x * 256 + tid;
    const int npair = (N + 1) >> 1;
    int pc = 0, sz = 0;
    if (i < npair) {
        int c0 = cnt[2 * i];
        int c1 = (2 * i + 1 < N) ? cnt[2 * i + 1] : 0;
        pc = (max(c0, c1) + 7) & ~7;
        sz = 2 * pc;
    }
    s[tid] = sz;
    __syncthreads();
    for (int o = 1; o < 256; o <<= 1) {
        int t = (tid >= o) ? s[tid - o] : 0;
        __syncthreads();
        s[tid] += t;
        __syncthreads();
    }
    if (i < npair) {
        int b = bsum[blockIdx.x] + s[tid] - sz;   // exclusive within block
        off[2 * i] = b;
        if (2 * i + 1 < N) off[2 * i + 1] = b + pc;
    }
}

// XCD-sliced scatter fill: group = blockIdx%8 handles dst slice
// [grp*per, (grp+1)*per). Each slice's csr window is contiguous (off is
// monotone) and written by one XCD's blocks -> full-line writebacks.
__global__ __launch_bounds__(256) void k_fillx(
        const int* __restrict__ esrc, const int* __restrict__ edst,
        const float* __restrict__ ew, const int* __restrict__ off,
        int* __restrict__ fill, unsigned* __restrict__ csr, int E, int N) {
    const int grp  = blockIdx.x & 7;
    const int gblk = blockIdx.x >> 3;
    const int nblk = gridDim.x >> 3;
    const int per  = (N + 7) >> 3;
    const int lo   = grp * per;
    const int hi   = min(N, lo + per);
    const int stride = nblk * blockDim.x;
    for (int e = gblk * blockDim.x + threadIdx.x; e < E; e += stride) {
        int d = edst[e];
        if (d < lo || d >= hi) continue;
        int p = atomicAdd(&fill[d], 1);
        unsigned h15 = (unsigned)__half_as_ushort(__float2half_rn(ew[e])) & 0x7FFFu;
        csr[off[d] + p] = ((unsigned)esrc[e] & SRC17) | (h15 << 17);
    }
}

// ---- fallback kernels ----
__global__ void k_fill_pad(const int* __restrict__ esrc, const int* __restrict__ edst,
                           const float* __restrict__ ew, int* __restrict__ fill,
                           int2* __restrict__ csr, int E, int CAP) {
    int e = blockIdx.x * blockDim.x + threadIdx.x;
    if (e < E) {
        int d = edst[e];
        int p = atomicAdd(&fill[d], 1);
        if (p < CAP)
            csr[(size_t)d * CAP + p] = make_int2(esrc[e], __float_as_int(ew[e]));
    }
}

__global__ void k_off(const int* __restrict__ cnt, int* __restrict__ off,
                      int* __restrict__ fill, int* __restrict__ cursor, int N) {
    int i    = blockIdx.x * blockDim.x + threadIdx.x;
    int lane = threadIdx.x & 63;
    int c    = (i < N) ? cnt[i] : 0;
    int pref = c;
    #pragma unroll
    for (int d = 1; d < 64; d <<= 1) {
        int t = __shfl_up(pref, d);
        if (lane >= d) pref += t;
    }
    int total = __shfl(pref, 63);
    int base  = 0;
    if (lane == 63) base = atomicAdd(cursor, total);
    base = __shfl(base, 63);
    if (i < N) {
        int p = base + pref - c;
        off[i]  = p;
        fill[i] = p;
    }
}

__global__ void k_fill(const int* __restrict__ esrc, const int* __restrict__ edst,
                       const float* __restrict__ ew, int* __restrict__ fill,
                       int2* __restrict__ csr, int E) {
    int e = blockIdx.x * blockDim.x + threadIdx.x;
    if (e < E) {
        int d = edst[e];
        int p = atomicAdd(&fill[d], 1);
        csr[p] = make_int2(esrc[e], __float_as_int(ew[e]));
    }
}

// main-path gather-aggregate: wave = node PAIR. slot=lane>>5 owns node
// 2p+slot; f8=lane&31 covers the full 64-feat row as half2. Edge stream is
// packed 4 B, pair-padded to round8 with zeros -> guard-free inner loop,
// no shuffles, no cross-lane reductions.
__global__ __launch_bounds__(256, 6) void k_agg_p(
        const unsigned* __restrict__ xh, const int* __restrict__ off,
        const int* __restrict__ cnt_arr, const unsigned* __restrict__ csr,
        float* __restrict__ agg, int N) {
    const int lane = threadIdx.x & 63;
    const int slot = lane >> 5;
    const int f8   = lane & 31;
    const int wq   = (blockIdx.x * blockDim.x + threadIdx.x) >> 6;
    const int nw   = (gridDim.x * blockDim.x) >> 6;
    const int npair = (N + 1) >> 1;

    for (int pr = wq; pr < npair; pr += nw) {
        const int  node  = 2 * pr + slot;
        const bool valid = node < N;
        const int  cnt_s = valid ? cnt_arr[node] : 0;
        const int  st_s  = valid ? off[node] : 0;
        const int  cA = __builtin_amdgcn_readlane(cnt_s, 0);
        const int  cB = __builtin_amdgcn_readlane(cnt_s, 32);
        const int  pc = (max(cA, cB) + 7) & ~7;     // == k_offp2's pair pad

        float2 acc = {0.f, 0.f};
        float  sw  = 0.f;
        const unsigned* __restrict__ pS = csr + st_s;
        for (int k = 0; k < pc; k += 8) {
            // broadcast edge fetch: same addr across the slot's 32 lanes
            uint4 e0 = *(const uint4*)(pS + k);
            uint4 e1 = *(const uint4*)(pS + k + 4);
            unsigned ev[8] = {e0.x, e0.y, e0.z, e0.w, e1.x, e1.y, e1.z, e1.w};
            float    w[8];
            unsigned u[8];
            #pragma unroll
            for (int t = 0; t < 8; ++t) {
                unsigned e = ev[t];
                w[t] = __half2float(__ushort_as_half((unsigned short)(e >> 17)));
                u[t] = xh[((e & SRC17) << 5) | (unsigned)f8];
            }
            #pragma unroll
            for (int t = 0; t < 8; ++t) {
                float2 v = __half22float2(*(const __half2*)&u[t]);
                acc.x = fmaf(w[t], v.x, acc.x);
                acc.y = fmaf(w[t], v.y, acc.y);
                sw += w[t];
            }
        }
        if (valid) {
            float invw = (sw > 0.f) ? (1.f / sw) : 0.f;
            float invd = 1.f / ((float)cnt_s + 1.f);
            unsigned us = xh[((unsigned)node << 5) | (unsigned)f8];
            float2 xs = __half22float2(*(const __half2*)&us);
            float2 hn;
            hn.x = (acc.x * invw + xs.x) * invd;
            hn.y = (acc.y * invw + xs.y) * invd;
            ntstore_f2(&((float2*)agg)[(size_t)node * 32 + f8], hn);
        }
    }
}

// fallback gather-aggregate (int2 csr, fp16 x).
__global__ __launch_bounds__(256, 4) void k_agg_f(
        const unsigned* __restrict__ xh, const int* __restrict__ off,
        const int* __restrict__ cnt_arr, const int2* __restrict__ csr,
        float* __restrict__ agg, int N, int CAP) {
    const int lane   = threadIdx.x & 63;
    const int slot   = lane >> 5;
    const int f8     = lane & 31;
    const int wave   = (blockIdx.x * blockDim.x + threadIdx.x) >> 6;
    const int nwaves = (gridDim.x * blockDim.x) >> 6;

    int node  = wave;
    int cnt_p = 0, start_p = 0;
    if (node < N) {
        cnt_p   = cnt_arr[node];
        start_p = (CAP > 0) ? node * CAP : off[node];
        if (CAP > 0) cnt_p = min(cnt_p, CAP);
    }
    for (; node < N; node += nwaves) {
        const int cnt = cnt_p, start = start_p;
        int nn = node + nwaves;
        if (nn < N) {
            cnt_p   = cnt_arr[nn];
            start_p = (CAP > 0) ? nn * CAP : off[nn];
            if (CAP > 0) cnt_p = min(cnt_p, CAP);
        }
        int2 ee = make_int2(0, 0);
        if (lane < cnt) ee = ntload_i2(&csr[start + lane]);
        float2 acc0 = {0.f, 0.f}, acc1 = {0.f, 0.f};
        float  sw = 0.0f;
        for (int bk = 0; bk < cnt; bk += 64) {
            int   s_l = ee.x;
            float w_l = __int_as_float(ee.y);
            int2 en = make_int2(0, 0);
            int  rem = cnt - bk - 64;
            if (lane < rem) en = ntload_i2(&csr[start + bk + 64 + lane]);
            sw += w_l;
            #pragma unroll
            for (int half = 0; half < 2; ++half) {
                float    w[16];
                unsigned u[16];
                #pragma unroll
                for (int k = 0; k < 16; ++k) {
                    int idx = half * 32 + 2 * k + slot;
                    int s   = __shfl(s_l, idx);
                    w[k]    = __shfl(w_l, idx);
                    u[k]    = xh[(size_t)s * 32 + f8];
                }
                #pragma unroll
                for (int k = 0; k < 16; k += 2) {
                    float2 v0 = __half22float2(*(const __half2*)&u[k]);
                    float2 v1 = __half22float2(*(const __half2*)&u[k + 1]);
                    acc0.x = fmaf(w[k],     v0.x, acc0.x);
                    acc0.y = fmaf(w[k],     v0.y, acc0.y);
                    acc1.x = fmaf(w[k + 1], v1.x, acc1.x);
                    acc1.y = fmaf(w[k + 1], v1.y, acc1.y);
                }
            }
            ee = en;
        }
        acc0.x += acc1.x; acc0.y += acc1.y;
        acc0.x += __shfl_xor(acc0.x, 32);
        acc0.y += __shfl_xor(acc0.y, 32);
        #pragma unroll
        for (int mask = 1; mask <= 32; mask <<= 1) sw += __shfl_xor(sw, mask);
        float invw = (sw > 0.0f) ? (1.0f / sw) : 0.0f;
        float invd = 1.0f / ((float)cnt + 1.0f);
        if (lane < 32) {
            unsigned us = xh[(size_t)node * 32 + f8];
            float2 xs = __half22float2(*(const __half2*)&us);
            float2 hn;
            hn.x = (acc0.x * invw + xs.x) * invd;
            hn.y = (acc0.y * invw + xs.y) * invd;
            ntstore_f2(&((float2*)agg)[(size_t)node * 32 + f8], hn);
        }
    }
}

// k_fc: h = relu(agg @ W + b), emitted as fp16 (feeds the next agg gather).
// Per-lane W column in regs; readlane inner.
__global__ __launch_bounds__(256) void k_fc(
        const float* __restrict__ agg, const float* __restrict__ W,
        const float* __restrict__ b, __half* __restrict__ outh, int N) {
    const int lane   = threadIdx.x & 63;
    const int wave   = (blockIdx.x * blockDim.x + threadIdx.x) >> 6;
    const int nwaves = (gridDim.x * blockDim.x) >> 6;
    float wc[64];
    #pragma unroll
    for (int f = 0; f < 64; ++f) wc[f] = W[f * 64 + lane];   // coalesced rows
    const float bias = b[lane];
    for (int node = wave; node < N; node += nwaves) {
        float hn = agg[(size_t)node * 64 + lane];
        float o0 = bias, o1 = 0.f, o2 = 0.f, o3 = 0.f;
        #pragma unroll
        for (int f = 0; f < 64; f += 4) {
            o0 = fmaf(readlane_f(hn, f),     wc[f],     o0);
            o1 = fmaf(readlane_f(hn, f + 1), wc[f + 1], o1);
            o2 = fmaf(readlane_f(hn, f + 2), wc[f + 2], o2);
            o3 = fmaf(readlane_f(hn, f + 3), wc[f + 3], o3);
        }
        float o = fmaxf((o0 + o1) + (o2 + o3), 0.0f);
        outh[(size_t)node * 64 + lane] = __float2half_rn(o);
    }
}

// fc (with relu) + mean-pool fused; gid sorted -> run-length flush.
__global__ __launch_bounds__(256) void k_fcpool(
        const float* __restrict__ agg, const float* __restrict__ W,
        const float* __restrict__ b, const int* __restrict__ gid,
        float* __restrict__ hg, float* __restrict__ cntg, int N) {
    const int lane   = threadIdx.x & 63;
    const int wave   = (blockIdx.x * blockDim.x + threadIdx.x) >> 6;
    const int nwaves = (gridDim.x * blockDim.x) >> 6;
    float wc[64];
    #pragma unroll
    for (int f = 0; f < 64; ++f) wc[f] = W[f * 64 + lane];
    const float bias = b[lane];
    const int per   = (N + nwaves - 1) / nwaves;
    const int start = wave * per;
    const int end   = min(N, start + per);
    if (start >= N) return;

    int   curg = -1;
    float acc  = 0.0f;
    int   c    = 0;
    for (int node = start; node < end; ++node) {
        float hn = agg[(size_t)node * 64 + lane];
        float o0 = bias, o1 = 0.f, o2 = 0.f, o3 = 0.f;
        #pragma unroll
        for (int f = 0; f < 64; f += 4) {
            o0 = fmaf(readlane_f(hn, f),     wc[f],     o0);
            o1 = fmaf(readlane_f(hn, f + 1), wc[f + 1], o1);
            o2 = fmaf(readlane_f(hn, f + 2), wc[f + 2], o2);
            o3 = fmaf(readlane_f(hn, f + 3), wc[f + 3], o3);
        }
        float o = fmaxf((o0 + o1) + (o2 + o3), 0.0f);
        int g = gid[node];
        if (g != curg) {
            if (c > 0) {
                atomicAdd(&hg[curg * 64 + lane], acc);
                if (lane == 0) atomicAdd(&cntg[curg], (float)c);
            }
            curg = g; acc = 0.0f; c = 0;
        }
        acc += o;
        ++c;
    }
    if (c > 0) {
        atomicAdd(&hg[curg * 64 + lane], acc);
        if (lane == 0) atomicAdd(&cntg[curg], (float)c);
    }
}

__global__ void k_out(const float* __restrict__ hg, const float* __restrict__ cntg,
                      const float* __restrict__ Wc, const float* __restrict__ bc,
                      float* __restrict__ out, int G) {
    int t = blockIdx.x * blockDim.x + threadIdx.x;
    if (t >= G * 2) return;
    int g = t >> 1, c = t & 1;
    float ct = fmaxf(cntg[g], 1.0f);
    float o  = bc[c];
    for (int f = 0; f < 64; ++f)
        o += (hg[g * 64 + f] / ct) * Wc[f * 2 + c];
    out[t] = o;
}

extern "C" void kernel_launch(void* const* d_in, const int* in_sizes, int n_in,
                              void* d_out, int out_size, void* d_ws, size_t ws_size,
                              hipStream_t stream) {
    const float* in_feat = (const float*)d_in[0];
    const float* ew      = (const float*)d_in[1];
    const float* W1      = (const float*)d_in[2];
    const float* b1      = (const float*)d_in[3];
    const float* W2      = (const float*)d_in[4];
    const float* b2      = (const float*)d_in[5];
    const float* Wc      = (const float*)d_in[6];
    const float* bc      = (const float*)d_in[7];
    const int*   esrc    = (const int*)d_in[8];
    const int*   edst    = (const int*)d_in[9];
    const int*   gid     = (const int*)d_in[10];

    const int E = in_sizes[1];
    const int N = in_sizes[10];
    const int G = out_size / 2;
    float* outp = (float*)d_out;

    auto alignup = [](size_t x) { return (x + 15) & ~(size_t)15; };
    char* base = (char*)d_ws;
    const int FC_BLK = 1024, AGG_BLK = 2048;
    const int n4 = N * 16;                             // N*64/4 float4s
    const int npair = (N + 1) >> 1;
    const int nb    = (npair + 255) / 256;             // scan blocks (<=256)

    // ---- main path: direct pair-padded packed CSR, monotone off ----
    // csr capacity: sum 2*round8(max(c0,c1)) <= 2E + 8N
    size_t csr_cap = 2 * (size_t)E + 8 * (size_t)N;

    size_t zhdr  = ((size_t)G * 64 + G + 2 * (size_t)N + 256) * 4; // hg,cntg,cnt,fill,bsum
    size_t o_off = alignup(zhdr);
    size_t o_csr = o_off + alignup((size_t)N * 4);
    size_t o_t1  = o_csr + alignup(csr_cap * 4);
    size_t o_t2  = o_t1 + alignup((size_t)N * 64 * 4);
    size_t o_xh  = o_t2 + alignup((size_t)N * 64 * 4);
    size_t o_th  = o_xh + alignup((size_t)N * 64 * 2);
    size_t needB = o_th + (size_t)N * 64 * 2;

    if (ws_size >= needB && N <= (1 << 17)) {
        float*    hg   = (float*)base;
        float*    cntg = hg + (size_t)G * 64;
        int*      cnt  = (int*)(cntg + G);
        int*      fill = cnt + N;
        int*      bsum = fill + N;
        int*      off  = (int*)(base + o_off);
        unsigned* csr  = (unsigned*)(base + o_csr);
        float*    t1   = (float*)(base + o_t1);
        float*    t2   = (float*)(base + o_t2);
        unsigned* xh0  = (unsigned*)(base + o_xh);
        __half*   th1  = (__half*)(base + o_th);

        hipMemsetAsync(d_ws, 0, zhdr, stream);          // hg,cntg,cnt,fill,bsum
        hipMemsetAsync(csr, 0, csr_cap * 4, stream);    // pad slots stay 0
        k_cvt    <<<(n4 + 255) / 256, 256, 0, stream>>>((const float4*)in_feat, (uint2*)xh0, n4);
        k_cnt    <<<(E + 255) / 256, 256, 0, stream>>>(edst, cnt, E);
        k_psum   <<<nb, 256, 0, stream>>>(cnt, bsum, N);
        k_topscan<<<1, 256, 0, stream>>>(bsum, nb);
        k_offp2  <<<nb, 256, 0, stream>>>(cnt, bsum, off, N);
        k_fillx  <<<2048, 256, 0, stream>>>(esrc, edst, ew, off, fill, csr, E, N);
        k_agg_p <<<AGG_BLK, 256, 0, stream>>>(xh0, off, cnt, csr, t1, N);
        k_fc    <<<FC_BLK, 256, 0, stream>>>(t1, W1, b1, th1, N);
        k_agg_p <<<AGG_BLK, 256, 0, stream>>>((const unsigned*)th1, off, cnt, csr, t2, N);
        k_fcpool<<<FC_BLK, 256, 0, stream>>>(t2, W2, b2, gid, hg, cntg, N);
        k_out   <<<1, 128, 0, stream>>>(hg, cntg, Wc, bc, outp, G);
        return;
    }

    // ---- fallback 1: one-pass padded scatter + k_agg_f ----
    const int CAP = 96;
    size_t hdr    = ((size_t)G * 64 + G + 1 + N) * 4;
    size_t needB2 = alignup(hdr) + alignup((size_t)N * CAP * 8)
                  + alignup((size_t)N * 64 * 4) * 2
                  + alignup((size_t)N * 64 * 2) * 2;
    if (ws_size >= needB2) {
        size_t o = 0;
        float* hg     = (float*)(base + o);
        float* cntg   = hg + (size_t)G * 64;
        int*   fill   = (int*)(cntg + G) + 1;
        o += alignup(hdr);
        int2*     csr = (int2*)(base + o);    o += alignup((size_t)N * CAP * 8);
        float*    t1  = (float*)(base + o);   o += alignup((size_t)N * 64 * 4);
        float*    t2  = (float*)(base + o);   o += alignup((size_t)N * 64 * 4);
        unsigned* xh0 = (unsigned*)(base + o); o += alignup((size_t)N * 64 * 2);
        __half*   th1 = (__half*)(base + o);

        hipMemsetAsync(d_ws, 0, hdr, stream);
        k_cvt     <<<(n4 + 255) / 256, 256, 0, stream>>>((const float4*)in_feat, (uint2*)xh0, n4);
        k_fill_pad<<<(E + 255) / 256, 256, 0, stream>>>(esrc, edst, ew, fill, csr, E, CAP);
        k_agg_f <<<AGG_BLK, 256, 0, stream>>>(xh0, (const int*)nullptr, fill, csr, t1, N, CAP);
        k_fc    <<<FC_BLK, 256, 0, stream>>>(t1, W1, b1, th1, N);
        k_agg_f <<<AGG_BLK, 256, 0, stream>>>((const unsigned*)th1, (const int*)nullptr, fill, csr, t2, N, CAP);
        k_fcpool<<<FC_BLK, 256, 0, stream>>>(t2, W2, b2, gid, hg, cntg, N);
        k_out   <<<1, 128, 0, stream>>>(hg, cntg, Wc, bc, outp, G);
        return;
    }

    // ---- fallback 2: 3-pass compact CSR ----
    {
        size_t o = 0;
        float* hg     = (float*)(base + o);
        float* cntg   = hg + (size_t)G * 64;
        int*   cursor = (int*)(cntg + G);
        int*   cnt    = cursor + 1;
        o += alignup(hdr);
        int*      off  = (int*)(base + o);    o += alignup((size_t)N * 4);
        int*      fill = (int*)(base + o);    o += alignup((size_t)N * 4);
        int2*     csr  = (int2*)(base + o);   o += alignup((size_t)E * 8);
        float*    t1   = (float*)(base + o);  o += alignup((size_t)N * 64 * 4);
        float*    t2   = (float*)(base + o);  o += alignup((size_t)N * 64 * 4);
        unsigned* xh0  = (unsigned*)(base + o); o += alignup((size_t)N * 64 * 2);
        __half*   th1  = (__half*)(base + o);

        hipMemsetAsync(d_ws, 0, hdr, stream);
        k_cvt <<<(n4 + 255) / 256, 256, 0, stream>>>((const float4*)in_feat, (uint2*)xh0, n4);
        k_cnt <<<(E + 255) / 256, 256, 0, stream>>>(edst, cnt, E);
        k_off <<<(N + 255) / 256, 256, 0, stream>>>(cnt, off, fill, cursor, N);
        k_fill<<<(E + 255) / 256, 256, 0, stream>>>(esrc, edst, ew, fill, csr, E);
        k_agg_f <<<AGG_BLK, 256, 0, stream>>>(xh0, off, cnt, csr, t1, N, 0);
        k_fc    <<<FC_BLK, 256, 0, stream>>>(t1, W1, b1, th1, N);
        k_agg_f <<<AGG_BLK, 256, 0, stream>>>((const unsigned*)th1, off, cnt, csr, t2, N, 0);
        k_fcpool<<<FC_BLK, 256, 0, stream>>>(t2, W2, b2, gid, hg, cntg, N);
        k_out   <<<1, 128, 0, stream>>>(hg, cntg, Wc, bc, outp, G);
    }
}

// Round 5
// 401.267 us; speedup vs baseline: 1.6801x; 1.4403x over previous
//
#include <hip/hip_runtime.h>
#include <hip/hip_fp16.h>

// ---------------------------------------------------------------------------
// SGCN: 2-layer GraphSAGE('gcn') + EdgeWeightNorm('right') + mean-pool + FC
// N=100k nodes, E=3.2M edges, G=64 graphs, F=64 feats.
//
// R15 -> R16: revert to the R13 two-level pipeline (402us, the best verified
// structure) and replace ONLY binfill2:
//  * k_binA: scan-free direct-write binning. LDS hist (1024 buckets) ->
//    per-bucket global cursor reserve -> re-read chunk, LDS lcur atomic,
//    write 8B entry straight to bsw[b*CAPB+p]. No stg[] staging, no
//    18-barrier scan, no per-wave serial flush (the 95us latency sink).
//    Chunk's ~5-entry bucket runs are written concurrently to consecutive
//    addresses -> L2 merges lines (R2 measured 41MB WRITE for this layout).
//  * csrsort/agg_p/fc/fcpool identical to R13. off[] stays bucket-ordered
//    monotone (csrsort computes it), so agg keeps streaming csr reads.
// Pipeline: memset, cvt, binA, csrsort, agg, fc, agg, fcpool, out.
// ---------------------------------------------------------------------------

#define CH2  4096   // edges per binning block
#define BK   1024   // max buckets
#define NB   128    // nodes per bucket
#define CAPB 5120   // bucket raw capacity (mean 4096 + 16 sigma)
#define CAPP 6144   // bucket padded capacity (raw + pair-pad slack)
#define SRC17 0x1FFFFu

__device__ __forceinline__ float readlane_f(float v, int l) {
    return __int_as_float(__builtin_amdgcn_readlane(__float_as_int(v), l));
}

__device__ __forceinline__ int2 ntload_i2(const int2* p) {
    unsigned long long r = __builtin_nontemporal_load((const unsigned long long*)p);
    return make_int2((int)(unsigned)(r & 0xffffffffull), (int)(unsigned)(r >> 32));
}

__device__ __forceinline__ void ntstore_f2(float2* p, float2 v) {
    union { float2 f; unsigned long long u; } c;
    c.f = v;
    __builtin_nontemporal_store(c.u, (unsigned long long*)p);
}

// fp32 -> fp16 bulk convert (float4 -> 2x half2 per thread)
__global__ void k_cvt(const float4* __restrict__ x, uint2* __restrict__ xh, int n4) {
    int i = blockIdx.x * blockDim.x + threadIdx.x;
    if (i >= n4) return;
    float4 v = x[i];
    __half2 a = __floats2half2_rn(v.x, v.y);
    __half2 b = __floats2half2_rn(v.z, v.w);
    uint2 r;
    r.x = *(const unsigned*)&a;
    r.y = *(const unsigned*)&b;
    xh[i] = r;
}

// scan-free direct-write binning: LDS hist -> global span reserve ->
// direct scattered write into bucket regions (dl packed in .x bits 18..24).
__global__ __launch_bounds__(512) void k_binA(
        const int* __restrict__ esrc, const int* __restrict__ edst,
        const float* __restrict__ ew, int* __restrict__ cursor,
        int2* __restrict__ bsw, int E, int B) {
    __shared__ int h[BK];                // 4 KB
    __shared__ int lcur[BK];             // 4 KB
    const int tid = threadIdx.x;

    for (int i = tid; i < BK; i += 512) h[i] = 0;
    __syncthreads();
    const int e0 = blockIdx.x * CH2;
    const int e1 = min(E, e0 + CH2);
    for (int e = e0 + tid; e < e1; e += 512)
        atomicAdd(&h[edst[e] >> 7], 1);
    __syncthreads();
    for (int b = tid; b < BK; b += 512) {
        int c = h[b];
        lcur[b] = c ? atomicAdd(&cursor[b], c) : 0;
    }
    __syncthreads();
    for (int e = e0 + tid; e < e1; e += 512) {
        int d = edst[e];
        int b = d >> 7;
        int p = atomicAdd(&lcur[b], 1);
        if (p < CAPB)
            bsw[(size_t)b * CAPB + p] =
                make_int2(((d & 127) << 18) | esrc[e], __float_as_int(ew[e]));
    }
}

// counting-sort a bucket's edges in LDS; pair-padded packed flush.
// csr entry: src(17b) | fp16-weight-sans-sign(15b) << 17.
// Each node pair (2i,2i+1) gets round8(max(cntA,cntB)) slots each, pad = 0.
__global__ __launch_bounds__(512) void k_csrsort(
        const int2* __restrict__ bsw, const int* __restrict__ cursor,
        unsigned* __restrict__ csr, int* __restrict__ off, int* __restrict__ fill,
        int N) {
    __shared__ unsigned se[CAPP];        // 24 KB
    __shared__ int cur[NB];
    __shared__ int pfx[NB];
    __shared__ int tot;
    const int b = blockIdx.x, tid = threadIdx.x;
    for (int i = tid; i < CAPP; i += 512) se[i] = 0u;   // pad slots stay 0
    if (tid < NB) cur[tid] = 0;
    __syncthreads();
    const int cnt = min(cursor[b], CAPB);
    const int2* __restrict__ eb = bsw + (size_t)b * CAPB;
    for (int i = tid; i < cnt; i += 512)
        atomicAdd(&cur[eb[i].x >> 18], 1);   // pass1: counts
    __syncthreads();
    int pc = 0;
    if (tid < NB) {                          // pair-padded slot size
        int c0 = cur[tid & ~1], c1 = cur[tid | 1];
        pc = (max(c0, c1) + 7) & ~7;
        pfx[tid] = pc;
    }
    __syncthreads();
    for (int o = 1; o < NB; o <<= 1) {       // Hillis-Steele over 128
        int t = 0;
        if (tid < NB && tid >= o) t = pfx[tid - o];
        __syncthreads();
        if (tid < NB) pfx[tid] += t;
        __syncthreads();
    }
    if (tid < NB) {
        int excl = pfx[tid] - pc;
        int node = b * NB + tid;
        if (node < N) { off[node] = b * CAPP + excl; fill[node] = cur[tid]; }
        cur[tid] = excl;                     // reuse as scatter cursor
        if (tid == NB - 1) tot = min(pfx[tid], CAPP);
    }
    __syncthreads();
    for (int i = tid; i < cnt; i += 512) {
        int2 e = eb[i];
        int p = atomicAdd(&cur[e.x >> 18], 1);
        unsigned h15 = (unsigned)__half_as_ushort(
                           __float2half_rn(__int_as_float(e.y))) & 0x7FFFu;
        if (p < CAPP)
            se[p] = ((unsigned)e.x & SRC17) | (h15 << 17);   // pass2: packed
    }
    __syncthreads();
    const int T = tot;
    unsigned* __restrict__ cb = csr + (size_t)b * CAPP;
    for (int i = tid; i < T; i += 512) cb[i] = se[i];
}

// ---- fallback kernels ----
__global__ void k_fill_pad(const int* __restrict__ esrc, const int* __restrict__ edst,
                           const float* __restrict__ ew, int* __restrict__ fill,
                           int2* __restrict__ csr, int E, int CAP) {
    int e = blockIdx.x * blockDim.x + threadIdx.x;
    if (e < E) {
        int d = edst[e];
        int p = atomicAdd(&fill[d], 1);
        if (p < CAP)
            csr[(size_t)d * CAP + p] = make_int2(esrc[e], __float_as_int(ew[e]));
    }
}

__global__ void k_cnt(const int* __restrict__ edst, int* __restrict__ cnt, int E) {
    int e = blockIdx.x * blockDim.x + threadIdx.x;
    if (e < E) atomicAdd(&cnt[edst[e]], 1);
}

__global__ void k_off(const int* __restrict__ cnt, int* __restrict__ off,
                      int* __restrict__ fill, int* __restrict__ cursor, int N) {
    int i    = blockIdx.x * blockDim.x + threadIdx.x;
    int lane = threadIdx.x & 63;
    int c    = (i < N) ? cnt[i] : 0;
    int pref = c;
    #pragma unroll
    for (int d = 1; d < 64; d <<= 1) {
        int t = __shfl_up(pref, d);
        if (lane >= d) pref += t;
    }
    int total = __shfl(pref, 63);
    int base  = 0;
    if (lane == 63) base = atomicAdd(cursor, total);
    base = __shfl(base, 63);
    if (i < N) {
        int p = base + pref - c;
        off[i]  = p;
        fill[i] = p;
    }
}

__global__ void k_fill(const int* __restrict__ esrc, const int* __restrict__ edst,
                       const float* __restrict__ ew, int* __restrict__ fill,
                       int2* __restrict__ csr, int E) {
    int e = blockIdx.x * blockDim.x + threadIdx.x;
    if (e < E) {
        int d = edst[e];
        int p = atomicAdd(&fill[d], 1);
        csr[p] = make_int2(esrc[e], __float_as_int(ew[e]));
    }
}

// main-path gather-aggregate: wave = node PAIR. slot=lane>>5 owns node
// 2p+slot; f8=lane&31 covers the full 64-feat row as half2. Edge stream is
// packed 4 B, pair-padded to round8 with zeros -> guard-free inner loop,
// no shuffles, no cross-lane reductions.
__global__ __launch_bounds__(256, 6) void k_agg_p(
        const unsigned* __restrict__ xh, const int* __restrict__ off,
        const int* __restrict__ cnt_arr, const unsigned* __restrict__ csr,
        float* __restrict__ agg, int N) {
    const int lane = threadIdx.x & 63;
    const int slot = lane >> 5;
    const int f8   = lane & 31;
    const int wq   = (blockIdx.x * blockDim.x + threadIdx.x) >> 6;
    const int nw   = (gridDim.x * blockDim.x) >> 6;
    const int npair = (N + 1) >> 1;

    for (int pr = wq; pr < npair; pr += nw) {
        const int  node  = 2 * pr + slot;
        const bool valid = node < N;
        const int  cnt_s = valid ? cnt_arr[node] : 0;
        const int  st_s  = valid ? off[node] : 0;
        const int  cA = __builtin_amdgcn_readlane(cnt_s, 0);
        const int  cB = __builtin_amdgcn_readlane(cnt_s, 32);
        const int  pc = (max(cA, cB) + 7) & ~7;     // == csrsort's pair pad

        float2 acc = {0.f, 0.f};
        float  sw  = 0.f;
        const unsigned* __restrict__ pS = csr + st_s;
        for (int k = 0; k < pc; k += 8) {
            // broadcast edge fetch: same addr across the slot's 32 lanes
            uint4 e0 = *(const uint4*)(pS + k);
            uint4 e1 = *(const uint4*)(pS + k + 4);
            unsigned ev[8] = {e0.x, e0.y, e0.z, e0.w, e1.x, e1.y, e1.z, e1.w};
            float    w[8];
            unsigned u[8];
            #pragma unroll
            for (int t = 0; t < 8; ++t) {
                unsigned e = ev[t];
                w[t] = __half2float(__ushort_as_half((unsigned short)(e >> 17)));
                u[t] = xh[((e & SRC17) << 5) | (unsigned)f8];
            }
            #pragma unroll
            for (int t = 0; t < 8; ++t) {
                float2 v = __half22float2(*(const __half2*)&u[t]);
                acc.x = fmaf(w[t], v.x, acc.x);
                acc.y = fmaf(w[t], v.y, acc.y);
                sw += w[t];
            }
        }
        if (valid) {
            float invw = (sw > 0.f) ? (1.f / sw) : 0.f;
            float invd = 1.f / ((float)cnt_s + 1.f);
            unsigned us = xh[((unsigned)node << 5) | (unsigned)f8];
            float2 xs = __half22float2(*(const __half2*)&us);
            float2 hn;
            hn.x = (acc.x * invw + xs.x) * invd;
            hn.y = (acc.y * invw + xs.y) * invd;
            ntstore_f2(&((float2*)agg)[(size_t)node * 32 + f8], hn);
        }
    }
}

// fallback gather-aggregate (int2 csr, fp16 x).
__global__ __launch_bounds__(256, 4) void k_agg_f(
        const unsigned* __restrict__ xh, const int* __restrict__ off,
        const int* __restrict__ cnt_arr, const int2* __restrict__ csr,
        float* __restrict__ agg, int N, int CAP) {
    const int lane   = threadIdx.x & 63;
    const int slot   = lane >> 5;
    const int f8     = lane & 31;
    const int wave   = (blockIdx.x * blockDim.x + threadIdx.x) >> 6;
    const int nwaves = (gridDim.x * blockDim.x) >> 6;

    int node  = wave;
    int cnt_p = 0, start_p = 0;
    if (node < N) {
        cnt_p   = cnt_arr[node];
        start_p = (CAP > 0) ? node * CAP : off[node];
        if (CAP > 0) cnt_p = min(cnt_p, CAP);
    }
    for (; node < N; node += nwaves) {
        const int cnt = cnt_p, start = start_p;
        int nn = node + nwaves;
        if (nn < N) {
            cnt_p   = cnt_arr[nn];
            start_p = (CAP > 0) ? nn * CAP : off[nn];
            if (CAP > 0) cnt_p = min(cnt_p, CAP);
        }
        int2 ee = make_int2(0, 0);
        if (lane < cnt) ee = ntload_i2(&csr[start + lane]);
        float2 acc0 = {0.f, 0.f}, acc1 = {0.f, 0.f};
        float  sw = 0.0f;
        for (int bk = 0; bk < cnt; bk += 64) {
            int   s_l = ee.x;
            float w_l = __int_as_float(ee.y);
            int2 en = make_int2(0, 0);
            int  rem = cnt - bk - 64;
            if (lane < rem) en = ntload_i2(&csr[start + bk + 64 + lane]);
            sw += w_l;
            #pragma unroll
            for (int half = 0; half < 2; ++half) {
                float    w[16];
                unsigned u[16];
                #pragma unroll
                for (int k = 0; k < 16; ++k) {
                    int idx = half * 32 + 2 * k + slot;
                    int s   = __shfl(s_l, idx);
                    w[k]    = __shfl(w_l, idx);
                    u[k]    = xh[(size_t)s * 32 + f8];
                }
                #pragma unroll
                for (int k = 0; k < 16; k += 2) {
                    float2 v0 = __half22float2(*(const __half2*)&u[k]);
                    float2 v1 = __half22float2(*(const __half2*)&u[k + 1]);
                    acc0.x = fmaf(w[k],     v0.x, acc0.x);
                    acc0.y = fmaf(w[k],     v0.y, acc0.y);
                    acc1.x = fmaf(w[k + 1], v1.x, acc1.x);
                    acc1.y = fmaf(w[k + 1], v1.y, acc1.y);
                }
            }
            ee = en;
        }
        acc0.x += acc1.x; acc0.y += acc1.y;
        acc0.x += __shfl_xor(acc0.x, 32);
        acc0.y += __shfl_xor(acc0.y, 32);
        #pragma unroll
        for (int mask = 1; mask <= 32; mask <<= 1) sw += __shfl_xor(sw, mask);
        float invw = (sw > 0.0f) ? (1.0f / sw) : 0.0f;
        float invd = 1.0f / ((float)cnt + 1.0f);
        if (lane < 32) {
            unsigned us = xh[(size_t)node * 32 + f8];
            float2 xs = __half22float2(*(const __half2*)&us);
            float2 hn;
            hn.x = (acc0.x * invw + xs.x) * invd;
            hn.y = (acc0.y * invw + xs.y) * invd;
            ntstore_f2(&((float2*)agg)[(size_t)node * 32 + f8], hn);
        }
    }
}

// k_fc: h = relu(agg @ W + b), emitted as fp16 (feeds the next agg gather).
// Per-lane W column in regs; readlane inner.
__global__ __launch_bounds__(256) void k_fc(
        const float* __restrict__ agg, const float* __restrict__ W,
        const float* __restrict__ b, __half* __restrict__ outh, int N) {
    const int lane   = threadIdx.x & 63;
    const int wave   = (blockIdx.x * blockDim.x + threadIdx.x) >> 6;
    const int nwaves = (gridDim.x * blockDim.x) >> 6;
    float wc[64];
    #pragma unroll
    for (int f = 0; f < 64; ++f) wc[f] = W[f * 64 + lane];   // coalesced rows
    const float bias = b[lane];
    for (int node = wave; node < N; node += nwaves) {
        float hn = agg[(size_t)node * 64 + lane];
        float o0 = bias, o1 = 0.f, o2 = 0.f, o3 = 0.f;
        #pragma unroll
        for (int f = 0; f < 64; f += 4) {
            o0 = fmaf(readlane_f(hn, f),     wc[f],     o0);
            o1 = fmaf(readlane_f(hn, f + 1), wc[f + 1], o1);
            o2 = fmaf(readlane_f(hn, f + 2), wc[f + 2], o2);
            o3 = fmaf(readlane_f(hn, f + 3), wc[f + 3], o3);
        }
        float o = fmaxf((o0 + o1) + (o2 + o3), 0.0f);
        outh[(size_t)node * 64 + lane] = __float2half_rn(o);
    }
}

// fc (with relu) + mean-pool fused; gid sorted -> run-length flush.
__global__ __launch_bounds__(256) void k_fcpool(
        const float* __restrict__ agg, const float* __restrict__ W,
        const float* __restrict__ b, const int* __restrict__ gid,
        float* __restrict__ hg, float* __restrict__ cntg, int N) {
    const int lane   = threadIdx.x & 63;
    const int wave   = (blockIdx.x * blockDim.x + threadIdx.x) >> 6;
    const int nwaves = (gridDim.x * blockDim.x) >> 6;
    float wc[64];
    #pragma unroll
    for (int f = 0; f < 64; ++f) wc[f] = W[f * 64 + lane];
    const float bias = b[lane];
    const int per   = (N + nwaves - 1) / nwaves;
    const int start = wave * per;
    const int end   = min(N, start + per);
    if (start >= N) return;

    int   curg = -1;
    float acc  = 0.0f;
    int   c    = 0;
    for (int node = start; node < end; ++node) {
        float hn = agg[(size_t)node * 64 + lane];
        float o0 = bias, o1 = 0.f, o2 = 0.f, o3 = 0.f;
        #pragma unroll
        for (int f = 0; f < 64; f += 4) {
            o0 = fmaf(readlane_f(hn, f),     wc[f],     o0);
            o1 = fmaf(readlane_f(hn, f + 1), wc[f + 1], o1);
            o2 = fmaf(readlane_f(hn, f + 2), wc[f + 2], o2);
            o3 = fmaf(readlane_f(hn, f + 3), wc[f + 3], o3);
        }
        float o = fmaxf((o0 + o1) + (o2 + o3), 0.0f);
        int g = gid[node];
        if (g != curg) {
            if (c > 0) {
                atomicAdd(&hg[curg * 64 + lane], acc);
                if (lane == 0) atomicAdd(&cntg[curg], (float)c);
            }
            curg = g; acc = 0.0f; c = 0;
        }
        acc += o;
        ++c;
    }
    if (c > 0) {
        atomicAdd(&hg[curg * 64 + lane], acc);
        if (lane == 0) atomicAdd(&cntg[curg], (float)c);
    }
}

__global__ void k_out(const float* __restrict__ hg, const float* __restrict__ cntg,
                      const float* __restrict__ Wc, const float* __restrict__ bc,
                      float* __restrict__ out, int G) {
    int t = blockIdx.x * blockDim.x + threadIdx.x;
    if (t >= G * 2) return;
    int g = t >> 1, c = t & 1;
    float ct = fmaxf(cntg[g], 1.0f);
    float o  = bc[c];
    for (int f = 0; f < 64; ++f)
        o += (hg[g * 64 + f] / ct) * Wc[f * 2 + c];
    out[t] = o;
}

extern "C" void kernel_launch(void* const* d_in, const int* in_sizes, int n_in,
                              void* d_out, int out_size, void* d_ws, size_t ws_size,
                              hipStream_t stream) {
    const float* in_feat = (const float*)d_in[0];
    const float* ew      = (const float*)d_in[1];
    const float* W1      = (const float*)d_in[2];
    const float* b1      = (const float*)d_in[3];
    const float* W2      = (const float*)d_in[4];
    const float* b2      = (const float*)d_in[5];
    const float* Wc      = (const float*)d_in[6];
    const float* bc      = (const float*)d_in[7];
    const int*   esrc    = (const int*)d_in[8];
    const int*   edst    = (const int*)d_in[9];
    const int*   gid     = (const int*)d_in[10];

    const int E = in_sizes[1];
    const int N = in_sizes[10];
    const int G = out_size / 2;
    float* outp = (float*)d_out;

    auto alignup = [](size_t x) { return (x + 15) & ~(size_t)15; };
    char* base = (char*)d_ws;
    const int FC_BLK = 1024, AGG_BLK = 2048;
    const int n4 = N * 16;                             // N*64/4 float4s

    // ---- main path: two-level binning, packed pair-padded CSR ----
    const int B     = (N + NB - 1) / NB;               // 128-node buckets
    const int NBLK2 = (E + CH2 - 1) / CH2;

    size_t zhdr  = ((size_t)G * 64 + G + BK) * 4;      // hg, cntg, cursor
    size_t o_off = alignup(zhdr);
    size_t o_fil = o_off + alignup((size_t)N * 4);
    size_t o_bsw = o_fil + alignup((size_t)N * 4);
    size_t o_csr = o_bsw + alignup((size_t)B * CAPB * 8);
    size_t o_t1  = o_csr + alignup((size_t)B * CAPP * 4);
    size_t o_t2  = o_t1 + alignup((size_t)N * 64 * 4);
    size_t o_xh  = o_t2 + alignup((size_t)N * 64 * 4);
    size_t o_th  = o_xh + alignup((size_t)N * 64 * 2);
    size_t needB = o_th + (size_t)N * 64 * 2;

    bool cap_ok = ((size_t)E / B) + 512 < CAPB && N <= (1 << 17);

    if (ws_size >= needB && B <= BK && cap_ok) {
        float*    hg     = (float*)base;
        float*    cntg   = hg + (size_t)G * 64;
        int*      cursor = (int*)(cntg + G);
        int*      off    = (int*)(base + o_off);
        int*      fill   = (int*)(base + o_fil);
        int2*     bsw    = (int2*)(base + o_bsw);
        unsigned* csr    = (unsigned*)(base + o_csr);
        float*    t1     = (float*)(base + o_t1);
        float*    t2     = (float*)(base + o_t2);
        unsigned* xh0    = (unsigned*)(base + o_xh);
        __half*   th1    = (__half*)(base + o_th);

        hipMemsetAsync(d_ws, 0, zhdr, stream);   // hg, cntg, cursor
        k_cvt    <<<(n4 + 255) / 256, 256, 0, stream>>>((const float4*)in_feat, (uint2*)xh0, n4);
        k_binA   <<<NBLK2, 512, 0, stream>>>(esrc, edst, ew, cursor, bsw, E, B);
        k_csrsort<<<B, 512, 0, stream>>>(bsw, cursor, csr, off, fill, N);
        k_agg_p <<<AGG_BLK, 256, 0, stream>>>(xh0, off, fill, csr, t1, N);
        k_fc    <<<FC_BLK, 256, 0, stream>>>(t1, W1, b1, th1, N);
        k_agg_p <<<AGG_BLK, 256, 0, stream>>>((const unsigned*)th1, off, fill, csr, t2, N);
        k_fcpool<<<FC_BLK, 256, 0, stream>>>(t2, W2, b2, gid, hg, cntg, N);
        k_out   <<<1, 128, 0, stream>>>(hg, cntg, Wc, bc, outp, G);
        return;
    }

    // ---- fallback 1: one-pass padded scatter + k_agg_f ----
    const int CAP = 96;
    size_t hdr    = ((size_t)G * 64 + G + 1 + N) * 4;
    size_t needB2 = alignup(hdr) + alignup((size_t)N * CAP * 8)
                  + alignup((size_t)N * 64 * 4) * 2
                  + alignup((size_t)N * 64 * 2) * 2;
    if (ws_size >= needB2) {
        size_t o = 0;
        float* hg     = (float*)(base + o);
        float* cntg   = hg + (size_t)G * 64;
        int*   fill   = (int*)(cntg + G) + 1;
        o += alignup(hdr);
        int2*     csr = (int2*)(base + o);    o += alignup((size_t)N * CAP * 8);
        float*    t1  = (float*)(base + o);   o += alignup((size_t)N * 64 * 4);
        float*    t2  = (float*)(base + o);   o += alignup((size_t)N * 64 * 4);
        unsigned* xh0 = (unsigned*)(base + o); o += alignup((size_t)N * 64 * 2);
        __half*   th1 = (__half*)(base + o);

        hipMemsetAsync(d_ws, 0, hdr, stream);
        k_cvt     <<<(n4 + 255) / 256, 256, 0, stream>>>((const float4*)in_feat, (uint2*)xh0, n4);
        k_fill_pad<<<(E + 255) / 256, 256, 0, stream>>>(esrc, edst, ew, fill, csr, E, CAP);
        k_agg_f <<<AGG_BLK, 256, 0, stream>>>(xh0, (const int*)nullptr, fill, csr, t1, N, CAP);
        k_fc    <<<FC_BLK, 256, 0, stream>>>(t1, W1, b1, th1, N);
        k_agg_f <<<AGG_BLK, 256, 0, stream>>>((const unsigned*)th1, (const int*)nullptr, fill, csr, t2, N, CAP);
        k_fcpool<<<FC_BLK, 256, 0, stream>>>(t2, W2, b2, gid, hg, cntg, N);
        k_out   <<<1, 128, 0, stream>>>(hg, cntg, Wc, bc, outp, G);
        return;
    }

    // ---- fallback 2: 3-pass compact CSR ----
    {
        size_t o = 0;
        float* hg     = (float*)(base + o);
        float* cntg   = hg + (size_t)G * 64;
        int*   cursor = (int*)(cntg + G);
        int*   cnt    = cursor + 1;
        o += alignup(hdr);
        int*      off  = (int*)(base + o);    o += alignup((size_t)N * 4);
        int*      fill = (int*)(base + o);    o += alignup((size_t)N * 4);
        int2*     csr  = (int2*)(base + o);   o += alignup((size_t)E * 8);
        float*    t1   = (float*)(base + o);  o += alignup((size_t)N * 64 * 4);
        float*    t2   = (float*)(base + o);  o += alignup((size_t)N * 64 * 4);
        unsigned* xh0  = (unsigned*)(base + o); o += alignup((size_t)N * 64 * 2);
        __half*   th1  = (__half*)(base + o);

        hipMemsetAsync(d_ws, 0, hdr, stream);
        k_cvt <<<(n4 + 255) / 256, 256, 0, stream>>>((const float4*)in_feat, (uint2*)xh0, n4);
        k_cnt <<<(E + 255) / 256, 256, 0, stream>>>(edst, cnt, E);
        k_off <<<(N + 255) / 256, 256, 0, stream>>>(cnt, off, fill, cursor, N);
        k_fill<<<(E + 255) / 256, 256, 0, stream>>>(esrc, edst, ew, fill, csr, E);
        k_agg_f <<<AGG_BLK, 256, 0, stream>>>(xh0, off, cnt, csr, t1, N, 0);
        k_fc    <<<FC_BLK, 256, 0, stream>>>(t1, W1, b1, th1, N);
        k_agg_f <<<AGG_BLK, 256, 0, stream>>>((const unsigned*)th1, off, cnt, csr, t2, N, 0);
        k_fcpool<<<FC_BLK, 256, 0, stream>>>(t2, W2, b2, gid, hg, cntg, N);
        k_out   <<<1, 128, 0, stream>>>(hg, cntg, Wc, bc, outp, G);
    }
}

// Round 6
// 375.003 us; speedup vs baseline: 1.7978x; 1.0700x over previous
//
#include <hip/hip_runtime.h>
#include <hip/hip_fp16.h>

// ---------------------------------------------------------------------------
// SGCN: 2-layer GraphSAGE('gcn') + EdgeWeightNorm('right') + mean-pool + FC
// N=100k nodes, E=3.2M edges, G=64 graphs, F=64 feats.
//
// R16 -> R17:
//  * k_binA (92us) was bound by random partial-line DRAM writes: 4096-edge
//    chunks -> 5.2-entry (42B) runs per bucket -> RFO + DRAM RMW + row miss
//    per run (VALU 2%, HBM 16%, WRITE 93MB: nothing on-chip busy).
//  * k_binB: same 3-phase structure, but 256 blocks x 1024 threads,
//    chunk = E/256 ~ 12.5k edges -> 16-entry (128B, 2-full-line) runs.
//    Stores become full-line writebacks; each bucket touched by 256 not 782
//    chunks. LDS 8KB unchanged.
//  * csrsort/agg_p/fc/fcpool byte-identical to the verified 401us build.
// Pipeline: memset, cvt, binB, csrsort, agg, fc, agg, fcpool, out.
// ---------------------------------------------------------------------------

#define BK   1024   // max buckets
#define NB   128    // nodes per bucket
#define CAPB 5120   // bucket raw capacity (mean 4096 + 16 sigma)
#define CAPP 6144   // bucket padded capacity (raw + pair-pad slack)
#define SRC17 0x1FFFFu

__device__ __forceinline__ float readlane_f(float v, int l) {
    return __int_as_float(__builtin_amdgcn_readlane(__float_as_int(v), l));
}

__device__ __forceinline__ int2 ntload_i2(const int2* p) {
    unsigned long long r = __builtin_nontemporal_load((const unsigned long long*)p);
    return make_int2((int)(unsigned)(r & 0xffffffffull), (int)(unsigned)(r >> 32));
}

__device__ __forceinline__ void ntstore_f2(float2* p, float2 v) {
    union { float2 f; unsigned long long u; } c;
    c.f = v;
    __builtin_nontemporal_store(c.u, (unsigned long long*)p);
}

// fp32 -> fp16 bulk convert (float4 -> 2x half2 per thread)
__global__ void k_cvt(const float4* __restrict__ x, uint2* __restrict__ xh, int n4) {
    int i = blockIdx.x * blockDim.x + threadIdx.x;
    if (i >= n4) return;
    float4 v = x[i];
    __half2 a = __floats2half2_rn(v.x, v.y);
    __half2 b = __floats2half2_rn(v.z, v.w);
    uint2 r;
    r.x = *(const unsigned*)&a;
    r.y = *(const unsigned*)&b;
    xh[i] = r;
}

// scan-free direct-write binning, line-sized runs: 256 blocks x 1024 thr,
// chunk = ceil(E/256) (~12.5k edges) -> ~16-entry (128B) runs per bucket.
// LDS hist -> per-bucket global span reserve -> direct write into bucket
// regions (dl packed in .x bits 18..24).
__global__ __launch_bounds__(1024) void k_binB(
        const int* __restrict__ esrc, const int* __restrict__ edst,
        const float* __restrict__ ew, int* __restrict__ cursor,
        int2* __restrict__ bsw, int E, int CH) {
    __shared__ int h[BK];                // 4 KB
    __shared__ int lcur[BK];             // 4 KB
    const int tid = threadIdx.x;

    if (tid < BK) h[tid] = 0;
    __syncthreads();
    const int e0 = blockIdx.x * CH;
    const int e1 = min(E, e0 + CH);
    for (int e = e0 + tid; e < e1; e += 1024)
        atomicAdd(&h[edst[e] >> 7], 1);
    __syncthreads();
    if (tid < BK) {
        int c = h[tid];
        lcur[tid] = c ? atomicAdd(&cursor[tid], c) : 0;
    }
    __syncthreads();
    for (int e = e0 + tid; e < e1; e += 1024) {
        int d = edst[e];
        int b = d >> 7;
        int p = atomicAdd(&lcur[b], 1);
        if (p < CAPB)
            bsw[(size_t)b * CAPB + p] =
                make_int2(((d & 127) << 18) | esrc[e], __float_as_int(ew[e]));
    }
}

// counting-sort a bucket's edges in LDS; pair-padded packed flush.
// csr entry: src(17b) | fp16-weight-sans-sign(15b) << 17.
// Each node pair (2i,2i+1) gets round8(max(cntA,cntB)) slots each, pad = 0.
__global__ __launch_bounds__(512) void k_csrsort(
        const int2* __restrict__ bsw, const int* __restrict__ cursor,
        unsigned* __restrict__ csr, int* __restrict__ off, int* __restrict__ fill,
        int N) {
    __shared__ unsigned se[CAPP];        // 24 KB
    __shared__ int cur[NB];
    __shared__ int pfx[NB];
    __shared__ int tot;
    const int b = blockIdx.x, tid = threadIdx.x;
    for (int i = tid; i < CAPP; i += 512) se[i] = 0u;   // pad slots stay 0
    if (tid < NB) cur[tid] = 0;
    __syncthreads();
    const int cnt = min(cursor[b], CAPB);
    const int2* __restrict__ eb = bsw + (size_t)b * CAPB;
    for (int i = tid; i < cnt; i += 512)
        atomicAdd(&cur[eb[i].x >> 18], 1);   // pass1: counts
    __syncthreads();
    int pc = 0;
    if (tid < NB) {                          // pair-padded slot size
        int c0 = cur[tid & ~1], c1 = cur[tid | 1];
        pc = (max(c0, c1) + 7) & ~7;
        pfx[tid] = pc;
    }
    __syncthreads();
    for (int o = 1; o < NB; o <<= 1) {       // Hillis-Steele over 128
        int t = 0;
        if (tid < NB && tid >= o) t = pfx[tid - o];
        __syncthreads();
        if (tid < NB) pfx[tid] += t;
        __syncthreads();
    }
    if (tid < NB) {
        int excl = pfx[tid] - pc;
        int node = b * NB + tid;
        if (node < N) { off[node] = b * CAPP + excl; fill[node] = cur[tid]; }
        cur[tid] = excl;                     // reuse as scatter cursor
        if (tid == NB - 1) tot = min(pfx[tid], CAPP);
    }
    __syncthreads();
    for (int i = tid; i < cnt; i += 512) {
        int2 e = eb[i];
        int p = atomicAdd(&cur[e.x >> 18], 1);
        unsigned h15 = (unsigned)__half_as_ushort(
                           __float2half_rn(__int_as_float(e.y))) & 0x7FFFu;
        if (p < CAPP)
            se[p] = ((unsigned)e.x & SRC17) | (h15 << 17);   // pass2: packed
    }
    __syncthreads();
    const int T = tot;
    unsigned* __restrict__ cb = csr + (size_t)b * CAPP;
    for (int i = tid; i < T; i += 512) cb[i] = se[i];
}

// ---- fallback kernels ----
__global__ void k_fill_pad(const int* __restrict__ esrc, const int* __restrict__ edst,
                           const float* __restrict__ ew, int* __restrict__ fill,
                           int2* __restrict__ csr, int E, int CAP) {
    int e = blockIdx.x * blockDim.x + threadIdx.x;
    if (e < E) {
        int d = edst[e];
        int p = atomicAdd(&fill[d], 1);
        if (p < CAP)
            csr[(size_t)d * CAP + p] = make_int2(esrc[e], __float_as_int(ew[e]));
    }
}

__global__ void k_cnt(const int* __restrict__ edst, int* __restrict__ cnt, int E) {
    int e = blockIdx.x * blockDim.x + threadIdx.x;
    if (e < E) atomicAdd(&cnt[edst[e]], 1);
}

__global__ void k_off(const int* __restrict__ cnt, int* __restrict__ off,
                      int* __restrict__ fill, int* __restrict__ cursor, int N) {
    int i    = blockIdx.x * blockDim.x + threadIdx.x;
    int lane = threadIdx.x & 63;
    int c    = (i < N) ? cnt[i] : 0;
    int pref = c;
    #pragma unroll
    for (int d = 1; d < 64; d <<= 1) {
        int t = __shfl_up(pref, d);
        if (lane >= d) pref += t;
    }
    int total = __shfl(pref, 63);
    int base  = 0;
    if (lane == 63) base = atomicAdd(cursor, total);
    base = __shfl(base, 63);
    if (i < N) {
        int p = base + pref - c;
        off[i]  = p;
        fill[i] = p;
    }
}

__global__ void k_fill(const int* __restrict__ esrc, const int* __restrict__ edst,
                       const float* __restrict__ ew, int* __restrict__ fill,
                       int2* __restrict__ csr, int E) {
    int e = blockIdx.x * blockDim.x + threadIdx.x;
    if (e < E) {
        int d = edst[e];
        int p = atomicAdd(&fill[d], 1);
        csr[p] = make_int2(esrc[e], __float_as_int(ew[e]));
    }
}

// main-path gather-aggregate: wave = node PAIR. slot=lane>>5 owns node
// 2p+slot; f8=lane&31 covers the full 64-feat row as half2. Edge stream is
// packed 4 B, pair-padded to round8 with zeros -> guard-free inner loop,
// no shuffles, no cross-lane reductions.
__global__ __launch_bounds__(256, 6) void k_agg_p(
        const unsigned* __restrict__ xh, const int* __restrict__ off,
        const int* __restrict__ cnt_arr, const unsigned* __restrict__ csr,
        float* __restrict__ agg, int N) {
    const int lane = threadIdx.x & 63;
    const int slot = lane >> 5;
    const int f8   = lane & 31;
    const int wq   = (blockIdx.x * blockDim.x + threadIdx.x) >> 6;
    const int nw   = (gridDim.x * blockDim.x) >> 6;
    const int npair = (N + 1) >> 1;

    for (int pr = wq; pr < npair; pr += nw) {
        const int  node  = 2 * pr + slot;
        const bool valid = node < N;
        const int  cnt_s = valid ? cnt_arr[node] : 0;
        const int  st_s  = valid ? off[node] : 0;
        const int  cA = __builtin_amdgcn_readlane(cnt_s, 0);
        const int  cB = __builtin_amdgcn_readlane(cnt_s, 32);
        const int  pc = (max(cA, cB) + 7) & ~7;     // == csrsort's pair pad

        float2 acc = {0.f, 0.f};
        float  sw  = 0.f;
        const unsigned* __restrict__ pS = csr + st_s;
        for (int k = 0; k < pc; k += 8) {
            // broadcast edge fetch: same addr across the slot's 32 lanes
            uint4 e0 = *(const uint4*)(pS + k);
            uint4 e1 = *(const uint4*)(pS + k + 4);
            unsigned ev[8] = {e0.x, e0.y, e0.z, e0.w, e1.x, e1.y, e1.z, e1.w};
            float    w[8];
            unsigned u[8];
            #pragma unroll
            for (int t = 0; t < 8; ++t) {
                unsigned e = ev[t];
                w[t] = __half2float(__ushort_as_half((unsigned short)(e >> 17)));
                u[t] = xh[((e & SRC17) << 5) | (unsigned)f8];
            }
            #pragma unroll
            for (int t = 0; t < 8; ++t) {
                float2 v = __half22float2(*(const __half2*)&u[t]);
                acc.x = fmaf(w[t], v.x, acc.x);
                acc.y = fmaf(w[t], v.y, acc.y);
                sw += w[t];
            }
        }
        if (valid) {
            float invw = (sw > 0.f) ? (1.f / sw) : 0.f;
            float invd = 1.f / ((float)cnt_s + 1.f);
            unsigned us = xh[((unsigned)node << 5) | (unsigned)f8];
            float2 xs = __half22float2(*(const __half2*)&us);
            float2 hn;
            hn.x = (acc.x * invw + xs.x) * invd;
            hn.y = (acc.y * invw + xs.y) * invd;
            ntstore_f2(&((float2*)agg)[(size_t)node * 32 + f8], hn);
        }
    }
}

// fallback gather-aggregate (int2 csr, fp16 x).
__global__ __launch_bounds__(256, 4) void k_agg_f(
        const unsigned* __restrict__ xh, const int* __restrict__ off,
        const int* __restrict__ cnt_arr, const int2* __restrict__ csr,
        float* __restrict__ agg, int N, int CAP) {
    const int lane   = threadIdx.x & 63;
    const int slot   = lane >> 5;
    const int f8     = lane & 31;
    const int wave   = (blockIdx.x * blockDim.x + threadIdx.x) >> 6;
    const int nwaves = (gridDim.x * blockDim.x) >> 6;

    int node  = wave;
    int cnt_p = 0, start_p = 0;
    if (node < N) {
        cnt_p   = cnt_arr[node];
        start_p = (CAP > 0) ? node * CAP : off[node];
        if (CAP > 0) cnt_p = min(cnt_p, CAP);
    }
    for (; node < N; node += nwaves) {
        const int cnt = cnt_p, start = start_p;
        int nn = node + nwaves;
        if (nn < N) {
            cnt_p   = cnt_arr[nn];
            start_p = (CAP > 0) ? nn * CAP : off[nn];
            if (CAP > 0) cnt_p = min(cnt_p, CAP);
        }
        int2 ee = make_int2(0, 0);
        if (lane < cnt) ee = ntload_i2(&csr[start + lane]);
        float2 acc0 = {0.f, 0.f}, acc1 = {0.f, 0.f};
        float  sw = 0.0f;
        for (int bk = 0; bk < cnt; bk += 64) {
            int   s_l = ee.x;
            float w_l = __int_as_float(ee.y);
            int2 en = make_int2(0, 0);
            int  rem = cnt - bk - 64;
            if (lane < rem) en = ntload_i2(&csr[start + bk + 64 + lane]);
            sw += w_l;
            #pragma unroll
            for (int half = 0; half < 2; ++half) {
                float    w[16];
                unsigned u[16];
                #pragma unroll
                for (int k = 0; k < 16; ++k) {
                    int idx = half * 32 + 2 * k + slot;
                    int s   = __shfl(s_l, idx);
                    w[k]    = __shfl(w_l, idx);
                    u[k]    = xh[(size_t)s * 32 + f8];
                }
                #pragma unroll
                for (int k = 0; k < 16; k += 2) {
                    float2 v0 = __half22float2(*(const __half2*)&u[k]);
                    float2 v1 = __half22float2(*(const __half2*)&u[k + 1]);
                    acc0.x = fmaf(w[k],     v0.x, acc0.x);
                    acc0.y = fmaf(w[k],     v0.y, acc0.y);
                    acc1.x = fmaf(w[k + 1], v1.x, acc1.x);
                    acc1.y = fmaf(w[k + 1], v1.y, acc1.y);
                }
            }
            ee = en;
        }
        acc0.x += acc1.x; acc0.y += acc1.y;
        acc0.x += __shfl_xor(acc0.x, 32);
        acc0.y += __shfl_xor(acc0.y, 32);
        #pragma unroll
        for (int mask = 1; mask <= 32; mask <<= 1) sw += __shfl_xor(sw, mask);
        float invw = (sw > 0.0f) ? (1.0f / sw) : 0.0f;
        float invd = 1.0f / ((float)cnt + 1.0f);
        if (lane < 32) {
            unsigned us = xh[(size_t)node * 32 + f8];
            float2 xs = __half22float2(*(const __half2*)&us);
            float2 hn;
            hn.x = (acc0.x * invw + xs.x) * invd;
            hn.y = (acc0.y * invw + xs.y) * invd;
            ntstore_f2(&((float2*)agg)[(size_t)node * 32 + f8], hn);
        }
    }
}

// k_fc: h = relu(agg @ W + b), emitted as fp16 (feeds the next agg gather).
// Per-lane W column in regs; readlane inner.
__global__ __launch_bounds__(256) void k_fc(
        const float* __restrict__ agg, const float* __restrict__ W,
        const float* __restrict__ b, __half* __restrict__ outh, int N) {
    const int lane   = threadIdx.x & 63;
    const int wave   = (blockIdx.x * blockDim.x + threadIdx.x) >> 6;
    const int nwaves = (gridDim.x * blockDim.x) >> 6;
    float wc[64];
    #pragma unroll
    for (int f = 0; f < 64; ++f) wc[f] = W[f * 64 + lane];   // coalesced rows
    const float bias = b[lane];
    for (int node = wave; node < N; node += nwaves) {
        float hn = agg[(size_t)node * 64 + lane];
        float o0 = bias, o1 = 0.f, o2 = 0.f, o3 = 0.f;
        #pragma unroll
        for (int f = 0; f < 64; f += 4) {
            o0 = fmaf(readlane_f(hn, f),     wc[f],     o0);
            o1 = fmaf(readlane_f(hn, f + 1), wc[f + 1], o1);
            o2 = fmaf(readlane_f(hn, f + 2), wc[f + 2], o2);
            o3 = fmaf(readlane_f(hn, f + 3), wc[f + 3], o3);
        }
        float o = fmaxf((o0 + o1) + (o2 + o3), 0.0f);
        outh[(size_t)node * 64 + lane] = __float2half_rn(o);
    }
}

// fc (with relu) + mean-pool fused; gid sorted -> run-length flush.
__global__ __launch_bounds__(256) void k_fcpool(
        const float* __restrict__ agg, const float* __restrict__ W,
        const float* __restrict__ b, const int* __restrict__ gid,
        float* __restrict__ hg, float* __restrict__ cntg, int N) {
    const int lane   = threadIdx.x & 63;
    const int wave   = (blockIdx.x * blockDim.x + threadIdx.x) >> 6;
    const int nwaves = (gridDim.x * blockDim.x) >> 6;
    float wc[64];
    #pragma unroll
    for (int f = 0; f < 64; ++f) wc[f] = W[f * 64 + lane];
    const float bias = b[lane];
    const int per   = (N + nwaves - 1) / nwaves;
    const int start = wave * per;
    const int end   = min(N, start + per);
    if (start >= N) return;

    int   curg = -1;
    float acc  = 0.0f;
    int   c    = 0;
    for (int node = start; node < end; ++node) {
        float hn = agg[(size_t)node * 64 + lane];
        float o0 = bias, o1 = 0.f, o2 = 0.f, o3 = 0.f;
        #pragma unroll
        for (int f = 0; f < 64; f += 4) {
            o0 = fmaf(readlane_f(hn, f),     wc[f],     o0);
            o1 = fmaf(readlane_f(hn, f + 1), wc[f + 1], o1);
            o2 = fmaf(readlane_f(hn, f + 2), wc[f + 2], o2);
            o3 = fmaf(readlane_f(hn, f + 3), wc[f + 3], o3);
        }
        float o = fmaxf((o0 + o1) + (o2 + o3), 0.0f);
        int g = gid[node];
        if (g != curg) {
            if (c > 0) {
                atomicAdd(&hg[curg * 64 + lane], acc);
                if (lane == 0) atomicAdd(&cntg[curg], (float)c);
            }
            curg = g; acc = 0.0f; c = 0;
        }
        acc += o;
        ++c;
    }
    if (c > 0) {
        atomicAdd(&hg[curg * 64 + lane], acc);
        if (lane == 0) atomicAdd(&cntg[curg], (float)c);
    }
}

__global__ void k_out(const float* __restrict__ hg, const float* __restrict__ cntg,
                      const float* __restrict__ Wc, const float* __restrict__ bc,
                      float* __restrict__ out, int G) {
    int t = blockIdx.x * blockDim.x + threadIdx.x;
    if (t >= G * 2) return;
    int g = t >> 1, c = t & 1;
    float ct = fmaxf(cntg[g], 1.0f);
    float o  = bc[c];
    for (int f = 0; f < 64; ++f)
        o += (hg[g * 64 + f] / ct) * Wc[f * 2 + c];
    out[t] = o;
}

extern "C" void kernel_launch(void* const* d_in, const int* in_sizes, int n_in,
                              void* d_out, int out_size, void* d_ws, size_t ws_size,
                              hipStream_t stream) {
    const float* in_feat = (const float*)d_in[0];
    const float* ew      = (const float*)d_in[1];
    const float* W1      = (const float*)d_in[2];
    const float* b1      = (const float*)d_in[3];
    const float* W2      = (const float*)d_in[4];
    const float* b2      = (const float*)d_in[5];
    const float* Wc      = (const float*)d_in[6];
    const float* bc      = (const float*)d_in[7];
    const int*   esrc    = (const int*)d_in[8];
    const int*   edst    = (const int*)d_in[9];
    const int*   gid     = (const int*)d_in[10];

    const int E = in_sizes[1];
    const int N = in_sizes[10];
    const int G = out_size / 2;
    float* outp = (float*)d_out;

    auto alignup = [](size_t x) { return (x + 15) & ~(size_t)15; };
    char* base = (char*)d_ws;
    const int FC_BLK = 1024, AGG_BLK = 2048;
    const int n4 = N * 16;                             // N*64/4 float4s

    // ---- main path: two-level binning (line-sized runs), packed CSR ----
    const int B   = (N + NB - 1) / NB;                 // 128-node buckets
    const int CHB = (E + 255) / 256;                   // edges per binB block

    size_t zhdr  = ((size_t)G * 64 + G + BK) * 4;      // hg, cntg, cursor
    size_t o_off = alignup(zhdr);
    size_t o_fil = o_off + alignup((size_t)N * 4);
    size_t o_bsw = o_fil + alignup((size_t)N * 4);
    size_t o_csr = o_bsw + alignup((size_t)B * CAPB * 8);
    size_t o_t1  = o_csr + alignup((size_t)B * CAPP * 4);
    size_t o_t2  = o_t1 + alignup((size_t)N * 64 * 4);
    size_t o_xh  = o_t2 + alignup((size_t)N * 64 * 4);
    size_t o_th  = o_xh + alignup((size_t)N * 64 * 2);
    size_t needB = o_th + (size_t)N * 64 * 2;

    bool cap_ok = ((size_t)E / B) + 512 < CAPB && N <= (1 << 17);

    if (ws_size >= needB && B <= BK && cap_ok) {
        float*    hg     = (float*)base;
        float*    cntg   = hg + (size_t)G * 64;
        int*      cursor = (int*)(cntg + G);
        int*      off    = (int*)(base + o_off);
        int*      fill   = (int*)(base + o_fil);
        int2*     bsw    = (int2*)(base + o_bsw);
        unsigned* csr    = (unsigned*)(base + o_csr);
        float*    t1     = (float*)(base + o_t1);
        float*    t2     = (float*)(base + o_t2);
        unsigned* xh0    = (unsigned*)(base + o_xh);
        __half*   th1    = (__half*)(base + o_th);

        hipMemsetAsync(d_ws, 0, zhdr, stream);   // hg, cntg, cursor
        k_cvt    <<<(n4 + 255) / 256, 256, 0, stream>>>((const float4*)in_feat, (uint2*)xh0, n4);
        k_binB   <<<256, 1024, 0, stream>>>(esrc, edst, ew, cursor, bsw, E, CHB);
        k_csrsort<<<B, 512, 0, stream>>>(bsw, cursor, csr, off, fill, N);
        k_agg_p <<<AGG_BLK, 256, 0, stream>>>(xh0, off, fill, csr, t1, N);
        k_fc    <<<FC_BLK, 256, 0, stream>>>(t1, W1, b1, th1, N);
        k_agg_p <<<AGG_BLK, 256, 0, stream>>>((const unsigned*)th1, off, fill, csr, t2, N);
        k_fcpool<<<FC_BLK, 256, 0, stream>>>(t2, W2, b2, gid, hg, cntg, N);
        k_out   <<<1, 128, 0, stream>>>(hg, cntg, Wc, bc, outp, G);
        return;
    }

    // ---- fallback 1: one-pass padded scatter + k_agg_f ----
    const int CAP = 96;
    size_t hdr    = ((size_t)G * 64 + G + 1 + N) * 4;
    size_t needB2 = alignup(hdr) + alignup((size_t)N * CAP * 8)
                  + alignup((size_t)N * 64 * 4) * 2
                  + alignup((size_t)N * 64 * 2) * 2;
    if (ws_size >= needB2) {
        size_t o = 0;
        float* hg     = (float*)(base + o);
        float* cntg   = hg + (size_t)G * 64;
        int*   fill   = (int*)(cntg + G) + 1;
        o += alignup(hdr);
        int2*     csr = (int2*)(base + o);    o += alignup((size_t)N * CAP * 8);
        float*    t1  = (float*)(base + o);   o += alignup((size_t)N * 64 * 4);
        float*    t2  = (float*)(base + o);   o += alignup((size_t)N * 64 * 4);
        unsigned* xh0 = (unsigned*)(base + o); o += alignup((size_t)N * 64 * 2);
        __half*   th1 = (__half*)(base + o);

        hipMemsetAsync(d_ws, 0, hdr, stream);
        k_cvt     <<<(n4 + 255) / 256, 256, 0, stream>>>((const float4*)in_feat, (uint2*)xh0, n4);
        k_fill_pad<<<(E + 255) / 256, 256, 0, stream>>>(esrc, edst, ew, fill, csr, E, CAP);
        k_agg_f <<<AGG_BLK, 256, 0, stream>>>(xh0, (const int*)nullptr, fill, csr, t1, N, CAP);
        k_fc    <<<FC_BLK, 256, 0, stream>>>(t1, W1, b1, th1, N);
        k_agg_f <<<AGG_BLK, 256, 0, stream>>>((const unsigned*)th1, (const int*)nullptr, fill, csr, t2, N, CAP);
        k_fcpool<<<FC_BLK, 256, 0, stream>>>(t2, W2, b2, gid, hg, cntg, N);
        k_out   <<<1, 128, 0, stream>>>(hg, cntg, Wc, bc, outp, G);
        return;
    }

    // ---- fallback 2: 3-pass compact CSR ----
    {
        size_t o = 0;
        float* hg     = (float*)(base + o);
        float* cntg   = hg + (size_t)G * 64;
        int*   cursor = (int*)(cntg + G);
        int*   cnt    = cursor + 1;
        o += alignup(hdr);
        int*      off  = (int*)(base + o);    o += alignup((size_t)N * 4);
        int*      fill = (int*)(base + o);    o += alignup((size_t)N * 4);
        int2*     csr  = (int2*)(base + o);   o += alignup((size_t)E * 8);
        float*    t1   = (float*)(base + o);  o += alignup((size_t)N * 64 * 4);
        float*    t2   = (float*)(base + o);  o += alignup((size_t)N * 64 * 4);
        unsigned* xh0  = (unsigned*)(base + o); o += alignup((size_t)N * 64 * 2);
        __half*   th1  = (__half*)(base + o);

        hipMemsetAsync(d_ws, 0, hdr, stream);
        k_cvt <<<(n4 + 255) / 256, 256, 0, stream>>>((const float4*)in_feat, (uint2*)xh0, n4);
        k_cnt <<<(E + 255) / 256, 256, 0, stream>>>(edst, cnt, E);
        k_off <<<(N + 255) / 256, 256, 0, stream>>>(cnt, off, fill, cursor, N);
        k_fill<<<(E + 255) / 256, 256, 0, stream>>>(esrc, edst, ew, fill, csr, E);
        k_agg_f <<<AGG_BLK, 256, 0, stream>>>(xh0, off, cnt, csr, t1, N, 0);
        k_fc    <<<FC_BLK, 256, 0, stream>>>(t1, W1, b1, th1, N);
        k_agg_f <<<AGG_BLK, 256, 0, stream>>>((const unsigned*)th1, off, cnt, csr, t2, N, 0);
        k_fcpool<<<FC_BLK, 256, 0, stream>>>(t2, W2, b2, gid, hg, cntg, N);
        k_out   <<<1, 128, 0, stream>>>(hg, cntg, Wc, bc, outp, G);
    }
}